// Round 15
// baseline (407.689 us; speedup 1.0000x reference)
//
#include <hip/hip_runtime.h>
#include <math.h>

typedef __attribute__((ext_vector_type(4)))  float    f32x4;
typedef __attribute__((ext_vector_type(16))) float    f32x16;
typedef __attribute__((ext_vector_type(2)))  _Float16 f16x2;
typedef __attribute__((ext_vector_type(4)))  _Float16 f16x4;
typedef __attribute__((ext_vector_type(8)))  _Float16 f16x8;
typedef __attribute__((ext_vector_type(4)))  unsigned u32x4;

constexpr int Bc  = 4;
constexpr int Tc  = 2048;
constexpr int Vc  = 2048;
constexpr int Dc  = 512;
constexpr int Hc  = 8;
constexpr int HDc = 64;
constexpr int Lc  = 4;
constexpr size_t SZe = (size_t)Bc * Tc * Dc;   // 4,194,304

// Fixed softmax offset (log2 domain). Scores*log2e max ~19; p <= 2^7, f16-safe.
constexpr float SM_C = 12.0f;

__device__ __forceinline__ void gload_lds16(const _Float16* g, _Float16* s) {
    __builtin_amdgcn_global_load_lds(
        (const __attribute__((address_space(1))) void*)g,
        (__attribute__((address_space(3))) void*)s,
        16, 0, 0);
}

__device__ __forceinline__ unsigned cvt_pk_u(float a, float b) {
    return __builtin_bit_cast(unsigned, __builtin_amdgcn_cvt_pkrtz(a, b));
}

// ---------------------------------------------------------------------------
// fp32 -> f16 bulk converts (weights/temb only; x is fused into embed_gemm)
// ---------------------------------------------------------------------------
__global__ __launch_bounds__(256) void cvt_k(
    const float* __restrict__ in, _Float16* __restrict__ out, int n4)
{
    for (int i = blockIdx.x * 256 + threadIdx.x; i < n4; i += gridDim.x * 256) {
        float4 v = ((const float4*)in)[i];
        f16x4 h = {(_Float16)v.x, (_Float16)v.y, (_Float16)v.z, (_Float16)v.w};
        *(f16x4*)&out[(size_t)i * 4] = h;
    }
}

__global__ __launch_bounds__(256) void cvtW_k(
    const float* __restrict__ a, const float* __restrict__ b,
    const float* __restrict__ c, const float* __restrict__ d,
    _Float16* __restrict__ oa, _Float16* __restrict__ ob,
    _Float16* __restrict__ oc, _Float16* __restrict__ od, int n4)
{
    const float* in; _Float16* out;
    switch (blockIdx.y) {
        case 0:  in = a; out = oa; break;
        case 1:  in = b; out = ob; break;
        case 2:  in = c; out = oc; break;
        default: in = d; out = od; break;
    }
    for (int i = blockIdx.x * 256 + threadIdx.x; i < n4; i += gridDim.x * 256) {
        float4 v = ((const float4*)in)[i];
        f16x4 h = {(_Float16)v.x, (_Float16)v.y, (_Float16)v.z, (_Float16)v.w};
        *(f16x4*)&out[(size_t)i * 4] = h;
    }
}

// ---------------------------------------------------------------------------
// Embed GEMM: h = x(fp32) @ temb16^T * s + pos.  BM=BN=64, BK=64, 256 thr =
// 4 waves (2x2, 32x32 out each).  A is fp32, reg-staged (issue-early loads,
// cvt+swizzled ds_write after compute); B f16 via gload_lds.  Counted vmcnt.
// Grid (M/64, N/64) = (128, 8) -> 4 blocks/CU.
// ---------------------------------------------------------------------------
__global__ __launch_bounds__(256) void embed_gemm(
    const float* __restrict__ A, const _Float16* __restrict__ W,
    _Float16* __restrict__ C, const float* __restrict__ pos,
    int K, float scale)
{
    __shared__ __align__(16) _Float16 LA[2][64 * 64];
    __shared__ __align__(16) _Float16 LB[2][64 * 64];

    const int tid = threadIdx.x;
    const int w  = tid >> 6, l = tid & 63;
    const int li = l & 15,  lg = l >> 4;
    const int wm = w >> 1,  wn = w & 1;
    const int m0 = blockIdx.x * 64;
    const int n0 = blockIdx.y * 64;

    // A sources (fp32, unswizzled; swizzle applied at ds_write)
    const float* srcA[2];
    int wrA[2];
#pragma unroll
    for (int c = 0; c < 2; ++c) {
        const int pb = tid * 32 + c * 16;        // byte off in 8KB f16 tile
        const int r = pb >> 7, cb = pb & 127;
        srcA[c] = A + (size_t)(m0 + r) * K + (cb >> 1);
        wrA[c] = r * 128 + (cb ^ ((r & 7) << 4));
    }
    // B sources (pre-swizzled global, linear LDS dest)
    const _Float16* srcB[2];
#pragma unroll
    for (int i = 0; i < 2; ++i) {
        const int d = i * 4096 + tid * 16;
        const int r = d >> 7, cb = (d & 127) ^ ((r & 7) << 4);
        srcB[i] = W + (size_t)(n0 + r) * K + (cb >> 1);
    }

    float4 ra[4];
    auto issueA = [&]() {
#pragma unroll
        for (int c = 0; c < 2; ++c) {
            ra[2 * c]     = *(const float4*)srcA[c];
            ra[2 * c + 1] = *(const float4*)(srcA[c] + 4);
            srcA[c] += 64;
        }
    };
    auto writeA = [&](int b) {
#pragma unroll
        for (int c = 0; c < 2; ++c) {
            f16x8 h = {(_Float16)ra[2*c].x,   (_Float16)ra[2*c].y,
                       (_Float16)ra[2*c].z,   (_Float16)ra[2*c].w,
                       (_Float16)ra[2*c+1].x, (_Float16)ra[2*c+1].y,
                       (_Float16)ra[2*c+1].z, (_Float16)ra[2*c+1].w};
            *(f16x8*)((char*)&LA[b][0] + wrA[c]) = h;
        }
    };
    auto stageB = [&](int b) {
#pragma unroll
        for (int i = 0; i < 2; ++i) { gload_lds16(srcB[i], &LB[b][i * 2048 + tid * 8]); srcB[i] += 64; }
    };

    f32x4 acc[2][2];
#pragma unroll
    for (int i = 0; i < 2; ++i)
#pragma unroll
        for (int j = 0; j < 2; ++j) acc[i][j] = (f32x4){0.f, 0.f, 0.f, 0.f};

    auto compute = [&](int b) {
        const char* Ab = (const char*)&LA[b][0];
        const char* Bb = (const char*)&LB[b][0];
        f16x8 af[2][2], bf[2][2];
#pragma unroll
        for (int mb = 0; mb < 2; ++mb) {
            const int row = wm * 32 + mb * 16 + li, sz = (row & 7) << 4;
#pragma unroll
            for (int fi = 0; fi < 2; ++fi)
                af[mb][fi] = *(const f16x8*)(Ab + row * 128 + ((fi * 64 + lg * 16) ^ sz));
        }
#pragma unroll
        for (int nb = 0; nb < 2; ++nb) {
            const int row = wn * 32 + nb * 16 + li, sz = (row & 7) << 4;
#pragma unroll
            for (int fi = 0; fi < 2; ++fi)
                bf[nb][fi] = *(const f16x8*)(Bb + row * 128 + ((fi * 64 + lg * 16) ^ sz));
        }
#pragma unroll
        for (int mb = 0; mb < 2; ++mb)
#pragma unroll
            for (int nb = 0; nb < 2; ++nb)
#pragma unroll
                for (int fi = 0; fi < 2; ++fi)
                    acc[mb][nb] = __builtin_amdgcn_mfma_f32_16x16x32_f16(
                        af[mb][fi], bf[nb][fi], acc[mb][nb], 0, 0, 0);
    };

    const int NTk = K >> 6;   // 32
    issueA(); stageB(0);
    asm volatile("s_waitcnt vmcnt(2)" ::: "memory");   // A(0) regs ready
    writeA(0);
    asm volatile("s_waitcnt lgkmcnt(0)" ::: "memory");

    for (int kt = 0; kt < NTk; ++kt) {
        const int cur = kt & 1;
        const bool more = kt + 1 < NTk;
        if (more) {
            issueA();           // 4 vmem
            stageB(cur ^ 1);    // 2 vmem
            asm volatile("s_waitcnt vmcnt(6)" ::: "memory");   // B(t) done
        } else {
            asm volatile("s_waitcnt vmcnt(0)" ::: "memory");
        }
        __builtin_amdgcn_s_barrier();
        __builtin_amdgcn_sched_barrier(0);
        compute(cur);
        __builtin_amdgcn_s_barrier();
        __builtin_amdgcn_sched_barrier(0);
        if (more) {
            asm volatile("s_waitcnt vmcnt(2)" ::: "memory");   // A(t+1) regs ready
            writeA(cur ^ 1);
            asm volatile("s_waitcnt lgkmcnt(0)" ::: "memory");
        }
    }

    // Epilogue: flat f16 [M][512] + fp32 pos add.  C/D: col=li(n), row=lg*4+r.
#pragma unroll
    for (int mb = 0; mb < 2; ++mb) {
#pragma unroll
        for (int nb = 0; nb < 2; ++nb) {
            const int mbase = m0 + wm * 32 + mb * 16 + lg * 4;
            const int nc    = n0 + wn * 32 + nb * 16 + li;
#pragma unroll
            for (int r = 0; r < 4; ++r) {
                const int m = mbase + r;
                float val = acc[mb][nb][r] * scale + pos[(size_t)(m & (Tc - 1)) * Dc + nc];
                C[(size_t)m * Dc + nc] = (_Float16)val;
            }
        }
    }
}

// ---------------------------------------------------------------------------
// Pipelined f16 MFMA GEMM, NT (unchanged r14): QKV / Wp.
// ---------------------------------------------------------------------------
template<bool QKV>
__global__ __launch_bounds__(256) void gemm_f16(
    const _Float16* __restrict__ A,
    const _Float16* __restrict__ W0, const _Float16* __restrict__ W1,
    const _Float16* __restrict__ W2,
    void* __restrict__ C0, const float* __restrict__ pos,
    int K, float scA, float scB)
{
    __shared__ __align__(16) _Float16 LA[2][128 * 64];
    __shared__ __align__(16) _Float16 LB[2][64 * 64];

    const int tid = threadIdx.x;
    const int w  = tid >> 6, l = tid & 63;
    const int li = l & 15,  lg = l >> 4;
    const int wm = w >> 1,  wn = w & 1;
    const int m0 = blockIdx.x * 128;

    int sec = 0, n0;
    const _Float16* Wb;
    if (QKV) {
        sec = blockIdx.y >> 3; n0 = (blockIdx.y & 7) * 64;
        Wb = (sec == 0) ? W0 : ((sec == 1) ? W1 : W2);
    } else {
        n0 = blockIdx.y * 64; Wb = W0;
    }
    const float scale = (sec == 0) ? scA : scB;

    const _Float16* srcA[4];
    const _Float16* srcB[2];
#pragma unroll
    for (int i = 0; i < 4; ++i) {
        const int d = i * 4096 + tid * 16;
        const int r = d >> 7, cb = (d & 127) ^ ((r & 7) << 4);
        srcA[i] = A + (size_t)(m0 + r) * K + (cb >> 1);
    }
#pragma unroll
    for (int i = 0; i < 2; ++i) {
        const int d = i * 4096 + tid * 16;
        const int r = d >> 7, cb = (d & 127) ^ ((r & 7) << 4);
        srcB[i] = Wb + (size_t)(n0 + r) * K + (cb >> 1);
    }

    auto stage = [&](int b) {
#pragma unroll
        for (int i = 0; i < 4; ++i) { gload_lds16(srcA[i], &LA[b][i * 2048 + tid * 8]); srcA[i] += 64; }
#pragma unroll
        for (int i = 0; i < 2; ++i) { gload_lds16(srcB[i], &LB[b][i * 2048 + tid * 8]); srcB[i] += 64; }
    };

    f32x4 acc[4][2];
#pragma unroll
    for (int i = 0; i < 4; ++i)
#pragma unroll
        for (int j = 0; j < 2; ++j) acc[i][j] = (f32x4){0.f, 0.f, 0.f, 0.f};

    auto compute = [&](int b) {
        const char* Ab = (const char*)&LA[b][0];
        const char* Bb = (const char*)&LB[b][0];
        f16x8 af[4][2], bf[2][2];
#pragma unroll
        for (int mb = 0; mb < 4; ++mb) {
            const int row = wm * 64 + mb * 16 + li, sz = (row & 7) << 4;
#pragma unroll
            for (int fi = 0; fi < 2; ++fi)
                af[mb][fi] = *(const f16x8*)(Ab + row * 128 + ((fi * 64 + lg * 16) ^ sz));
        }
#pragma unroll
        for (int nb = 0; nb < 2; ++nb) {
            const int row = wn * 32 + nb * 16 + li, sz = (row & 7) << 4;
#pragma unroll
            for (int fi = 0; fi < 2; ++fi)
                bf[nb][fi] = *(const f16x8*)(Bb + row * 128 + ((fi * 64 + lg * 16) ^ sz));
        }
#pragma unroll
        for (int mb = 0; mb < 4; ++mb)
#pragma unroll
            for (int nb = 0; nb < 2; ++nb)
#pragma unroll
                for (int fi = 0; fi < 2; ++fi)
                    acc[mb][nb] = __builtin_amdgcn_mfma_f32_16x16x32_f16(
                        af[mb][fi], bf[nb][fi], acc[mb][nb], 0, 0, 0);
    };

    const int NTk = K >> 6;
    stage(0);
    for (int kt = 0; kt < NTk; ++kt) {
        const int cur = kt & 1;
        if (kt + 1 < NTk) {
            stage(cur ^ 1);
            asm volatile("s_waitcnt vmcnt(6)" ::: "memory");
        } else {
            asm volatile("s_waitcnt vmcnt(0)" ::: "memory");
        }
        __builtin_amdgcn_s_barrier();
        __builtin_amdgcn_sched_barrier(0);
        compute(cur);
        __builtin_amdgcn_s_barrier();
        __builtin_amdgcn_sched_barrier(0);
    }

    // Epilogue. C/D: col(li) = n, row(lg*4+r) = m.
#pragma unroll
    for (int mb = 0; mb < 4; ++mb) {
#pragma unroll
        for (int nb = 0; nb < 2; ++nb) {
            const int mbase = m0 + wm * 64 + mb * 16 + lg * 4;
            const int nc    = n0 + wn * 32 + nb * 16 + li;
            if (QKV && sec == 2) {        // V frag-major (32x32), f16x4 store
                const int t0 = mbase & (Tc - 1);
                const int bh2 = (mbase >> 11) * Hc + (nc >> 6), d = nc & 63;
                f16x4 vv;
#pragma unroll
                for (int r = 0; r < 4; ++r) vv[r] = (_Float16)(acc[mb][nb][r] * scale);
                _Float16* vf = (_Float16*)C0 + 2 * SZe;
                const size_t adr =
                    (((size_t)bh2 * 32 + (t0 >> 6)) * 8 + (d >> 5) * 4 + ((t0 >> 4) & 3)) * 512
                    + ((d & 31) + 32 * ((t0 >> 3) & 1)) * 8 + (t0 & 7);
                *(f16x4*)&vf[adr] = vv;
            } else if (QKV && sec == 1) { // K frag-major (32x32), 2B scatter
                _Float16* kf = (_Float16*)C0 + SZe;
                const int t0 = mbase & (Tc - 1);
                const int bh2 = (mbase >> 11) * Hc + (nc >> 6), d = nc & 63;
                const size_t adr0 =
                    (((size_t)bh2 * 32 + (t0 >> 6)) * 8 + ((t0 >> 5) & 1) * 4 + (d >> 4)) * 512
                    + ((t0 & 31) + 32 * ((d >> 3) & 1)) * 8 + (d & 7);
#pragma unroll
                for (int r = 0; r < 4; ++r)
                    kf[adr0 + (size_t)r * 8] = (_Float16)(acc[mb][nb][r] * scale);
            } else if (QKV) {             // Q head-separated f16 [BH][T][64]
                _Float16* outp = (_Float16*)C0;
#pragma unroll
                for (int r = 0; r < 4; ++r) {
                    const int m = mbase + r, bb2 = m >> 11, t = m & (Tc - 1);
                    outp[(((size_t)bb2 * Hc + (nc >> 6)) * Tc + t) * HDc + (nc & 63)] =
                        (_Float16)(acc[mb][nb][r] * scale);
                }
            } else {                      // flat f16 [M][512]
                _Float16* outp = (_Float16*)C0;
#pragma unroll
                for (int r = 0; r < 4; ++r) {
                    const int m = mbase + r;
                    outp[(size_t)m * Dc + nc] = (_Float16)(acc[mb][nb][r] * scale);
                }
            }
        }
    }
}

// ---------------------------------------------------------------------------
// MFMA flash attention, all-register (r14 structure).  l-sum moved to the
// matrix pipe (ones-A mfma; C cols broadcast both lane-halves -> no shfl).
// ---------------------------------------------------------------------------
__global__ __launch_bounds__(256) void attn_mfma(
    const _Float16* __restrict__ Qh, const _Float16* __restrict__ Kf,
    const _Float16* __restrict__ Vf, _Float16* __restrict__ o)
{
    __shared__ float cm[4224];          // combine only: 2 qhalf x 64 x 33

    const int bid = blockIdx.x;
    const int bh  = bid & 31;           // XCD-locality: bid%8 == bh%8
    const int qt  = bid >> 5;
    const int hh  = bh & (Hc - 1);
    const int bb  = bh >> 3;
    const int tid = threadIdx.x;
    const int w   = tid >> 6;
    const int l   = tid & 63;
    const int li  = l & 31, lg2 = l >> 5;
    const int qhalf = w & 1, khalf = w >> 1;
    const int q0  = qt * 64 + qhalf * 32;

    const _Float16* Qb = Qh + (size_t)bh * Tc * HDc;
    f16x8 qf[4];
#pragma unroll
    for (int fi = 0; fi < 4; ++fi)
        qf[fi] = *(const f16x8*)&Qb[(size_t)(q0 + li) * HDc + fi * 16 + lg2 * 8];

    const _Float16* Kb  = Kf + (size_t)bh * Tc * HDc + (khalf * 4) * 512 + l * 8;
    const _Float16* Vb0 = Vf + (size_t)bh * Tc * HDc + (khalf * 2) * 512 + l * 8;
    const _Float16* Vb1 = Vb0 + 4 * 512;

    f32x16 oacc0, oacc1, lacc, sinit;
#pragma unroll
    for (int i = 0; i < 16; ++i) { oacc0[i] = 0.f; oacc1[i] = 0.f; lacc[i] = 0.f; sinit[i] = -SM_C; }
    f16x8 ones;
#pragma unroll
    for (int i = 0; i < 8; ++i) ones[i] = (_Float16)1.f;

    f16x8 kfr[4], vfr[4];
#pragma unroll
    for (int fi = 0; fi < 4; ++fi) kfr[fi] = *(const f16x8*)(Kb + fi * 512);
#pragma unroll
    for (int m = 0; m < 2; ++m) {
        vfr[m]     = *(const f16x8*)(Vb0 + m * 512);
        vfr[2 + m] = *(const f16x8*)(Vb1 + m * 512);
    }
    Kb += 4096; Vb0 += 4096; Vb1 += 4096;

    constexpr int NT = Tc / 64;
    for (int kt = 0; kt < NT; ++kt) {
        __builtin_amdgcn_s_setprio(1);
        f32x16 s = __builtin_amdgcn_mfma_f32_32x32x16_f16(kfr[0], qf[0], sinit, 0, 0, 0);
        s = __builtin_amdgcn_mfma_f32_32x32x16_f16(kfr[1], qf[1], s, 0, 0, 0);
        s = __builtin_amdgcn_mfma_f32_32x32x16_f16(kfr[2], qf[2], s, 0, 0, 0);
        s = __builtin_amdgcn_mfma_f32_32x32x16_f16(kfr[3], qf[3], s, 0, 0, 0);
        __builtin_amdgcn_s_setprio(0);

        if (kt + 1 < NT) {
#pragma unroll
            for (int fi = 0; fi < 4; ++fi) kfr[fi] = *(const f16x8*)(Kb + fi * 512);
            Kb += 4096;
        }

        // ---- max-free softmax: p = 2^s (l-sum happens on matrix pipe)
        unsigned cc[8];
#pragma unroll
        for (int g = 0; g < 4; ++g) {
            float p0 = __builtin_amdgcn_exp2f(s[4 * g + 0]);
            float p1 = __builtin_amdgcn_exp2f(s[4 * g + 1]);
            float p2 = __builtin_amdgcn_exp2f(s[4 * g + 2]);
            float p3 = __builtin_amdgcn_exp2f(s[4 * g + 3]);
            cc[2 * g]     = cvt_pk_u(p0, p1);
            cc[2 * g + 1] = cvt_pk_u(p2, p3);
        }

        f16x8 Bf[2];
#pragma unroll
        for (int m = 0; m < 2; ++m) {
            auto u = __builtin_amdgcn_permlane32_swap(cc[m * 4 + 0], cc[m * 4 + 2], false, false);
            auto v = __builtin_amdgcn_permlane32_swap(cc[m * 4 + 1], cc[m * 4 + 3], false, false);
            u32x4 b4 = (u32x4){u[0], v[0], u[1], v[1]};
            Bf[m] = __builtin_bit_cast(f16x8, b4);
        }

        __builtin_amdgcn_s_setprio(1);
        lacc  = __builtin_amdgcn_mfma_f32_32x32x16_f16(ones,   Bf[0], lacc,  0, 0, 0);
        oacc0 = __builtin_amdgcn_mfma_f32_32x32x16_f16(vfr[0], Bf[0], oacc0, 0, 0, 0);
        oacc0 = __builtin_amdgcn_mfma_f32_32x32x16_f16(vfr[1], Bf[1], oacc0, 0, 0, 0);
        lacc  = __builtin_amdgcn_mfma_f32_32x32x16_f16(ones,   Bf[1], lacc,  0, 0, 0);
        oacc1 = __builtin_amdgcn_mfma_f32_32x32x16_f16(vfr[2], Bf[0], oacc1, 0, 0, 0);
        oacc1 = __builtin_amdgcn_mfma_f32_32x32x16_f16(vfr[3], Bf[1], oacc1, 0, 0, 0);
        __builtin_amdgcn_s_setprio(0);

        if (kt + 1 < NT) {
#pragma unroll
            for (int m = 0; m < 2; ++m) {
                vfr[m]     = *(const f16x8*)(Vb0 + m * 512);
                vfr[2 + m] = *(const f16x8*)(Vb1 + m * 512);
            }
            Vb0 += 4096; Vb1 += 4096;
        }
    }

    // ---- combine k-halves (pure add thanks to max-free softmax)
    const float lrun_w = lacc[0];       // col q = l&31; both lane-halves hold it
    const int cbase = qhalf * (64 * 33) + l * 33;   // stride 33: conflict-free
    if (khalf == 1) {
#pragma unroll
        for (int i = 0; i < 16; ++i) cm[cbase + i]      = oacc0[i];
#pragma unroll
        for (int i = 0; i < 16; ++i) cm[cbase + 16 + i] = oacc1[i];
        cm[cbase + 32] = lrun_w;
    }
    __syncthreads();
    if (khalf == 0) {
#pragma unroll
        for (int i = 0; i < 16; ++i) oacc0[i] += cm[cbase + i];
#pragma unroll
        for (int i = 0; i < 16; ++i) oacc1[i] += cm[cbase + 16 + i];
        const float inv = 1.f / (lrun_w + cm[cbase + 32]);

        _Float16* op = o + ((size_t)(bb * Tc + q0 + li) * Dc + hh * HDc);
#pragma unroll
        for (int g = 0; g < 4; ++g) {
            const int d0 = 8 * g + 4 * lg2;
            f16x4 r0 = {(_Float16)(oacc0[4 * g + 0] * inv), (_Float16)(oacc0[4 * g + 1] * inv),
                        (_Float16)(oacc0[4 * g + 2] * inv), (_Float16)(oacc0[4 * g + 3] * inv)};
            f16x4 r1 = {(_Float16)(oacc1[4 * g + 0] * inv), (_Float16)(oacc1[4 * g + 1] * inv),
                        (_Float16)(oacc1[4 * g + 2] * inv), (_Float16)(oacc1[4 * g + 3] * inv)};
            *(f16x4*)(op + d0)      = r0;
            *(f16x4*)(op + 32 + d0) = r1;
        }
    }
}

// ---------------------------------------------------------------------------
__global__ __launch_bounds__(256) void readout_k(
    const _Float16* __restrict__ h, const float* __restrict__ ro,
    float* __restrict__ out, float scale)
{
    const int idx = blockIdx.x * 256 + threadIdx.x;
    const int vv  = idx & (Vc - 1);
    const int bb  = idx >> 11;
    const _Float16* hp = h + (size_t)(bb * Tc + (Tc - 1)) * Dc;
    const float* rp = ro + (size_t)vv * Dc;
    float ax = 0.f, ay = 0.f, az = 0.f, aw = 0.f;
#pragma unroll 8
    for (int i = 0; i < Dc / 4; ++i) {
        f16x4  hv = *(const f16x4*)(hp + i * 4);
        float4 rv = *(const float4*)(rp + i * 4);
        ax = fmaf((float)hv[0], rv.x, ax);
        ay = fmaf((float)hv[1], rv.y, ay);
        az = fmaf((float)hv[2], rv.z, az);
        aw = fmaf((float)hv[3], rv.w, aw);
    }
    out[idx] = ((ax + ay) + (az + aw)) * scale;
}

// ---------------------------------------------------------------------------
extern "C" void kernel_launch(void* const* d_in, const int* in_sizes, int n_in,
                              void* d_out, int out_size, void* d_ws, size_t ws_size,
                              hipStream_t stream)
{
    const float* x    = (const float*)d_in[0];
    const float* temb = (const float*)d_in[1];
    const float* pemb = (const float*)d_in[2];
    const float* Wk   = (const float*)d_in[3];
    const float* Wq   = (const float*)d_in[4];
    const float* Wv   = (const float*)d_in[5];
    const float* Wp   = (const float*)d_in[6];
    const float* ro   = (const float*)d_in[7];
    float* out = (float*)d_out;

    _Float16* h16    = (_Float16*)d_ws;                    // SZe
    _Float16* temb16 = h16 + SZe;                          // 1M
    _Float16* wq16   = temb16 + (size_t)Dc * Vc;           // 1M each
    _Float16* wk16   = wq16 + (size_t)Lc * Dc * Dc;
    _Float16* wv16   = wk16 + (size_t)Lc * Dc * Dc;
    _Float16* wp16   = wv16 + (size_t)Lc * Dc * Dc;
    _Float16* o16    = wp16 + (size_t)Lc * Dc * Dc;        // SZe
    _Float16* qh     = o16 + SZe;
    _Float16* khF    = qh + SZe;                           // frag-major K
    _Float16* vhF    = khF + SZe;                          // frag-major V

    const float s_emb  = 1.0f / sqrtf((float)Vc);
    const float s_proj = 1.0f / sqrtf((float)Dc);
    // Q scale: D^-1/2 * HD^-1/2 * log2(e)  (scores in log2 domain)
    const float s_q    = s_proj * 0.125f * 1.44269504f;

    const int W4 = Lc * Dc * Dc / 4;
    cvt_k<<<512, 256, 0, stream>>>(temb, temb16, Dc * Vc / 4);
    cvtW_k<<<dim3(512, 4), 256, 0, stream>>>(Wq, Wk, Wv, Wp,
                                             wq16, wk16, wv16, wp16, W4);

    // h = x(fp32) @ temb^T * s_emb + pos  (fused cvt; grid 1024 = 4/CU)
    embed_gemm<<<dim3(128, 8), 256, 0, stream>>>(x, temb16, h16, pemb, Vc, s_emb);

    const size_t WOFF = (size_t)Dc * Dc;
    for (int lyr = 0; lyr < Lc; ++lyr) {
        gemm_f16<true><<<dim3(64, 24), 256, 0, stream>>>(
            h16, wq16 + lyr * WOFF, wk16 + lyr * WOFF, wv16 + lyr * WOFF,
            qh, nullptr, Dc, s_q, s_proj);

        attn_mfma<<<Bc * Hc * (Tc / 64), 256, 0, stream>>>(qh, khF, vhF, o16);

        gemm_f16<false><<<dim3(64, 8), 256, 0, stream>>>(
            o16, wp16 + lyr * WOFF, nullptr, nullptr, h16, nullptr, Dc, s_proj, s_proj);
    }

    readout_k<<<(Bc * Vc) / 256, 256, 0, stream>>>(h16, ro, out, s_proj);
}

// Round 17
// 382.965 us; speedup vs baseline: 1.0646x; 1.0646x over previous
//
#include <hip/hip_runtime.h>
#include <math.h>

typedef __attribute__((ext_vector_type(4)))  float    f32x4;
typedef __attribute__((ext_vector_type(16))) float    f32x16;
typedef __attribute__((ext_vector_type(2)))  _Float16 f16x2;
typedef __attribute__((ext_vector_type(4)))  _Float16 f16x4;
typedef __attribute__((ext_vector_type(8)))  _Float16 f16x8;
typedef __attribute__((ext_vector_type(4)))  unsigned u32x4;

constexpr int Bc  = 4;
constexpr int Tc  = 2048;
constexpr int Vc  = 2048;
constexpr int Dc  = 512;
constexpr int Hc  = 8;
constexpr int HDc = 64;
constexpr int Lc  = 4;
constexpr size_t SZe = (size_t)Bc * Tc * Dc;   // 4,194,304

// Fixed softmax offset (log2 domain). Scores*log2e max ~19; p <= 2^7, f16-safe.
constexpr float SM_C = 12.0f;

__device__ __forceinline__ void gload_lds16(const _Float16* g, _Float16* s) {
    __builtin_amdgcn_global_load_lds(
        (const __attribute__((address_space(1))) void*)g,
        (__attribute__((address_space(3))) void*)s,
        16, 0, 0);
}

__device__ __forceinline__ unsigned cvt_pk_u(float a, float b) {
    return __builtin_bit_cast(unsigned, __builtin_amdgcn_cvt_pkrtz(a, b));
}

// ---------------------------------------------------------------------------
// fp32 -> f16 bulk converts
// ---------------------------------------------------------------------------
__global__ __launch_bounds__(256) void cvt_k(
    const float* __restrict__ in, _Float16* __restrict__ out, int n4)
{
    for (int i = blockIdx.x * 256 + threadIdx.x; i < n4; i += gridDim.x * 256) {
        float4 v = ((const float4*)in)[i];
        f16x4 h = {(_Float16)v.x, (_Float16)v.y, (_Float16)v.z, (_Float16)v.w};
        *(f16x4*)&out[(size_t)i * 4] = h;
    }
}

__global__ __launch_bounds__(256) void cvtW_k(
    const float* __restrict__ a, const float* __restrict__ b,
    const float* __restrict__ c, const float* __restrict__ d,
    _Float16* __restrict__ oa, _Float16* __restrict__ ob,
    _Float16* __restrict__ oc, _Float16* __restrict__ od, int n4)
{
    const float* in; _Float16* out;
    switch (blockIdx.y) {
        case 0:  in = a; out = oa; break;
        case 1:  in = b; out = ob; break;
        case 2:  in = c; out = oc; break;
        default: in = d; out = od; break;
    }
    for (int i = blockIdx.x * 256 + threadIdx.x; i < n4; i += gridDim.x * 256) {
        float4 v = ((const float4*)in)[i];
        f16x4 h = {(_Float16)v.x, (_Float16)v.y, (_Float16)v.z, (_Float16)v.w};
        *(f16x4*)&out[(size_t)i * 4] = h;
    }
}

// ---------------------------------------------------------------------------
// Frag-major K/V global layouts for 32x32x16 MFMA (per bh, tile TT = t>>6,
// 8 blocks x 512 halves per 64-token tile; lane l reads 16B at blk*1024B+l*16B):
//  K blk = ((t>>5)&1)*4 + (d>>4):  lane'=(t&31)+32*((d>>3)&1), j=d&7
//  V blk = (d>>5)*4 + ((t>>4)&3):  lane'=(d&31)+32*((t>>3)&1), j=t&7
// ---------------------------------------------------------------------------

// ---------------------------------------------------------------------------
// Pipelined f16 MFMA GEMM, NT: C = scale * A[M,K] @ W[N,K]^T.
// m0 = (blockIdx.x*mstep + moff)*128 (last-layer truncation support);
// y = blockIdx.y + ybase; QKV: sec = y>>3 -> {Q,K,V}.
// ---------------------------------------------------------------------------
template<bool QKV>
__global__ __launch_bounds__(256) void gemm_f16(
    const _Float16* __restrict__ A,
    const _Float16* __restrict__ W0, const _Float16* __restrict__ W1,
    const _Float16* __restrict__ W2,
    void* __restrict__ C0, const float* __restrict__ pos,
    int K, float scA, float scB, int mstep, int moff, int ybase)
{
    __shared__ __align__(16) _Float16 LA[2][128 * 64];
    __shared__ __align__(16) _Float16 LB[2][64 * 64];

    const int tid = threadIdx.x;
    const int w  = tid >> 6, l = tid & 63;
    const int li = l & 15,  lg = l >> 4;
    const int wm = w >> 1,  wn = w & 1;
    const int m0 = (blockIdx.x * mstep + moff) * 128;
    const int y  = blockIdx.y + ybase;

    int sec = 0, n0;
    const _Float16* Wb;
    if (QKV) {
        sec = y >> 3; n0 = (y & 7) * 64;
        Wb = (sec == 0) ? W0 : ((sec == 1) ? W1 : W2);
    } else {
        n0 = y * 64; Wb = W0;
    }
    const float scale = (sec == 0) ? scA : scB;

    const _Float16* srcA[4];
    const _Float16* srcB[2];
#pragma unroll
    for (int i = 0; i < 4; ++i) {
        const int d = i * 4096 + tid * 16;
        const int r = d >> 7, cb = (d & 127) ^ ((r & 7) << 4);
        srcA[i] = A + (size_t)(m0 + r) * K + (cb >> 1);
    }
#pragma unroll
    for (int i = 0; i < 2; ++i) {
        const int d = i * 4096 + tid * 16;
        const int r = d >> 7, cb = (d & 127) ^ ((r & 7) << 4);
        srcB[i] = Wb + (size_t)(n0 + r) * K + (cb >> 1);
    }

    auto stage = [&](int b) {
#pragma unroll
        for (int i = 0; i < 4; ++i) { gload_lds16(srcA[i], &LA[b][i * 2048 + tid * 8]); srcA[i] += 64; }
#pragma unroll
        for (int i = 0; i < 2; ++i) { gload_lds16(srcB[i], &LB[b][i * 2048 + tid * 8]); srcB[i] += 64; }
    };

    f32x4 acc[4][2];
#pragma unroll
    for (int i = 0; i < 4; ++i)
#pragma unroll
        for (int j = 0; j < 2; ++j) acc[i][j] = (f32x4){0.f, 0.f, 0.f, 0.f};

    auto compute = [&](int b) {
        const char* Ab = (const char*)&LA[b][0];
        const char* Bb = (const char*)&LB[b][0];
        f16x8 af[4][2], bf[2][2];
#pragma unroll
        for (int mb = 0; mb < 4; ++mb) {
            const int row = wm * 64 + mb * 16 + li, sz = (row & 7) << 4;
#pragma unroll
            for (int fi = 0; fi < 2; ++fi)
                af[mb][fi] = *(const f16x8*)(Ab + row * 128 + ((fi * 64 + lg * 16) ^ sz));
        }
#pragma unroll
        for (int nb = 0; nb < 2; ++nb) {
            const int row = wn * 32 + nb * 16 + li, sz = (row & 7) << 4;
#pragma unroll
            for (int fi = 0; fi < 2; ++fi)
                bf[nb][fi] = *(const f16x8*)(Bb + row * 128 + ((fi * 64 + lg * 16) ^ sz));
        }
#pragma unroll
        for (int mb = 0; mb < 4; ++mb)
#pragma unroll
            for (int nb = 0; nb < 2; ++nb)
#pragma unroll
                for (int fi = 0; fi < 2; ++fi)
                    acc[mb][nb] = __builtin_amdgcn_mfma_f32_16x16x32_f16(
                        af[mb][fi], bf[nb][fi], acc[mb][nb], 0, 0, 0);
    };

    const int NTk = K >> 6;
    stage(0);
    for (int kt = 0; kt < NTk; ++kt) {
        const int cur = kt & 1;
        if (kt + 1 < NTk) {
            stage(cur ^ 1);
            asm volatile("s_waitcnt vmcnt(6)" ::: "memory");
        } else {
            asm volatile("s_waitcnt vmcnt(0)" ::: "memory");
        }
        __builtin_amdgcn_s_barrier();
        __builtin_amdgcn_sched_barrier(0);
        compute(cur);
        __builtin_amdgcn_s_barrier();
        __builtin_amdgcn_sched_barrier(0);
    }

    // Epilogue. C/D: col(li) = n, row(lg*4+r) = m.
#pragma unroll
    for (int mb = 0; mb < 4; ++mb) {
#pragma unroll
        for (int nb = 0; nb < 2; ++nb) {
            const int mbase = m0 + wm * 64 + mb * 16 + lg * 4;
            const int nc    = n0 + wn * 32 + nb * 16 + li;
            if (QKV && sec == 2) {        // V frag-major (32x32), f16x4 store
                const int t0 = mbase & (Tc - 1);
                const int bh2 = (mbase >> 11) * Hc + (nc >> 6), d = nc & 63;
                f16x4 vv;
#pragma unroll
                for (int r = 0; r < 4; ++r) vv[r] = (_Float16)(acc[mb][nb][r] * scale);
                _Float16* vf = (_Float16*)C0 + 2 * SZe;
                const size_t adr =
                    (((size_t)bh2 * 32 + (t0 >> 6)) * 8 + (d >> 5) * 4 + ((t0 >> 4) & 3)) * 512
                    + ((d & 31) + 32 * ((t0 >> 3) & 1)) * 8 + (t0 & 7);
                *(f16x4*)&vf[adr] = vv;
            } else if (QKV && sec == 1) { // K frag-major (32x32), 2B scatter
                _Float16* kf = (_Float16*)C0 + SZe;
                const int t0 = mbase & (Tc - 1);
                const int bh2 = (mbase >> 11) * Hc + (nc >> 6), d = nc & 63;
                const size_t adr0 =
                    (((size_t)bh2 * 32 + (t0 >> 6)) * 8 + ((t0 >> 5) & 1) * 4 + (d >> 4)) * 512
                    + ((t0 & 31) + 32 * ((d >> 3) & 1)) * 8 + (d & 7);
#pragma unroll
                for (int r = 0; r < 4; ++r)
                    kf[adr0 + (size_t)r * 8] = (_Float16)(acc[mb][nb][r] * scale);
            } else if (QKV) {             // Q head-separated f16 [BH][T][64]
                _Float16* outp = (_Float16*)C0;
#pragma unroll
                for (int r = 0; r < 4; ++r) {
                    const int m = mbase + r, bb2 = m >> 11, t = m & (Tc - 1);
                    outp[(((size_t)bb2 * Hc + (nc >> 6)) * Tc + t) * HDc + (nc & 63)] =
                        (_Float16)(acc[mb][nb][r] * scale);
                }
            } else {                      // flat f16 [M][512] (+ fp32 pos add)
                _Float16* outp = (_Float16*)C0;
#pragma unroll
                for (int r = 0; r < 4; ++r) {
                    const int m = mbase + r;
                    float val = acc[mb][nb][r] * scale;
                    if (pos) val += pos[(size_t)(m & (Tc - 1)) * Dc + nc];
                    outp[(size_t)m * Dc + nc] = (_Float16)val;
                }
            }
        }
    }
}

// ---------------------------------------------------------------------------
// MFMA flash attention, all-register (r15 structure; l-sum on matrix pipe).
// qt = (bid>>5) + qtoff supports last-layer truncation (only qt=31 tile).
// ---------------------------------------------------------------------------
__global__ __launch_bounds__(256) void attn_mfma(
    const _Float16* __restrict__ Qh, const _Float16* __restrict__ Kf,
    const _Float16* __restrict__ Vf, _Float16* __restrict__ o, int qtoff)
{
    __shared__ float cm[4224];          // combine only: 2 qhalf x 64 x 33

    const int bid = blockIdx.x;
    const int bh  = bid & 31;           // XCD-locality: bid%8 == bh%8
    const int qt  = (bid >> 5) + qtoff;
    const int hh  = bh & (Hc - 1);
    const int bb  = bh >> 3;
    const int tid = threadIdx.x;
    const int w   = tid >> 6;
    const int l   = tid & 63;
    const int li  = l & 31, lg2 = l >> 5;
    const int qhalf = w & 1, khalf = w >> 1;
    const int q0  = qt * 64 + qhalf * 32;

    const _Float16* Qb = Qh + (size_t)bh * Tc * HDc;
    f16x8 qf[4];
#pragma unroll
    for (int fi = 0; fi < 4; ++fi)
        qf[fi] = *(const f16x8*)&Qb[(size_t)(q0 + li) * HDc + fi * 16 + lg2 * 8];

    const _Float16* Kb  = Kf + (size_t)bh * Tc * HDc + (khalf * 4) * 512 + l * 8;
    const _Float16* Vb0 = Vf + (size_t)bh * Tc * HDc + (khalf * 2) * 512 + l * 8;
    const _Float16* Vb1 = Vb0 + 4 * 512;

    f32x16 oacc0, oacc1, lacc, sinit;
#pragma unroll
    for (int i = 0; i < 16; ++i) { oacc0[i] = 0.f; oacc1[i] = 0.f; lacc[i] = 0.f; sinit[i] = -SM_C; }
    f16x8 ones;
#pragma unroll
    for (int i = 0; i < 8; ++i) ones[i] = (_Float16)1.f;

    f16x8 kfr[4], vfr[4];
#pragma unroll
    for (int fi = 0; fi < 4; ++fi) kfr[fi] = *(const f16x8*)(Kb + fi * 512);
#pragma unroll
    for (int m = 0; m < 2; ++m) {
        vfr[m]     = *(const f16x8*)(Vb0 + m * 512);
        vfr[2 + m] = *(const f16x8*)(Vb1 + m * 512);
    }
    Kb += 4096; Vb0 += 4096; Vb1 += 4096;

    constexpr int NT = Tc / 64;
    for (int kt = 0; kt < NT; ++kt) {
        __builtin_amdgcn_s_setprio(1);
        f32x16 s = __builtin_amdgcn_mfma_f32_32x32x16_f16(kfr[0], qf[0], sinit, 0, 0, 0);
        s = __builtin_amdgcn_mfma_f32_32x32x16_f16(kfr[1], qf[1], s, 0, 0, 0);
        s = __builtin_amdgcn_mfma_f32_32x32x16_f16(kfr[2], qf[2], s, 0, 0, 0);
        s = __builtin_amdgcn_mfma_f32_32x32x16_f16(kfr[3], qf[3], s, 0, 0, 0);
        __builtin_amdgcn_s_setprio(0);

        if (kt + 1 < NT) {
#pragma unroll
            for (int fi = 0; fi < 4; ++fi) kfr[fi] = *(const f16x8*)(Kb + fi * 512);
            Kb += 4096;
        }

        unsigned cc[8];
#pragma unroll
        for (int g = 0; g < 4; ++g) {
            float p0 = __builtin_amdgcn_exp2f(s[4 * g + 0]);
            float p1 = __builtin_amdgcn_exp2f(s[4 * g + 1]);
            float p2 = __builtin_amdgcn_exp2f(s[4 * g + 2]);
            float p3 = __builtin_amdgcn_exp2f(s[4 * g + 3]);
            cc[2 * g]     = cvt_pk_u(p0, p1);
            cc[2 * g + 1] = cvt_pk_u(p2, p3);
        }

        f16x8 Bf[2];
#pragma unroll
        for (int m = 0; m < 2; ++m) {
            auto u = __builtin_amdgcn_permlane32_swap(cc[m * 4 + 0], cc[m * 4 + 2], false, false);
            auto v = __builtin_amdgcn_permlane32_swap(cc[m * 4 + 1], cc[m * 4 + 3], false, false);
            u32x4 b4 = (u32x4){u[0], v[0], u[1], v[1]};
            Bf[m] = __builtin_bit_cast(f16x8, b4);
        }

        __builtin_amdgcn_s_setprio(1);
        lacc  = __builtin_amdgcn_mfma_f32_32x32x16_f16(ones,   Bf[0], lacc,  0, 0, 0);
        oacc0 = __builtin_amdgcn_mfma_f32_32x32x16_f16(vfr[0], Bf[0], oacc0, 0, 0, 0);
        oacc0 = __builtin_amdgcn_mfma_f32_32x32x16_f16(vfr[1], Bf[1], oacc0, 0, 0, 0);
        lacc  = __builtin_amdgcn_mfma_f32_32x32x16_f16(ones,   Bf[1], lacc,  0, 0, 0);
        oacc1 = __builtin_amdgcn_mfma_f32_32x32x16_f16(vfr[2], Bf[0], oacc1, 0, 0, 0);
        oacc1 = __builtin_amdgcn_mfma_f32_32x32x16_f16(vfr[3], Bf[1], oacc1, 0, 0, 0);
        __builtin_amdgcn_s_setprio(0);

        if (kt + 1 < NT) {
#pragma unroll
            for (int m = 0; m < 2; ++m) {
                vfr[m]     = *(const f16x8*)(Vb0 + m * 512);
                vfr[2 + m] = *(const f16x8*)(Vb1 + m * 512);
            }
            Vb0 += 4096; Vb1 += 4096;
        }
    }

    const float lrun_w = lacc[0];       // col q = l&31; both lane-halves hold it
    const int cbase = qhalf * (64 * 33) + l * 33;
    if (khalf == 1) {
#pragma unroll
        for (int i = 0; i < 16; ++i) cm[cbase + i]      = oacc0[i];
#pragma unroll
        for (int i = 0; i < 16; ++i) cm[cbase + 16 + i] = oacc1[i];
        cm[cbase + 32] = lrun_w;
    }
    __syncthreads();
    if (khalf == 0) {
#pragma unroll
        for (int i = 0; i < 16; ++i) oacc0[i] += cm[cbase + i];
#pragma unroll
        for (int i = 0; i < 16; ++i) oacc1[i] += cm[cbase + 16 + i];
        const float inv = 1.f / (lrun_w + cm[cbase + 32]);

        _Float16* op = o + ((size_t)(bb * Tc + q0 + li) * Dc + hh * HDc);
#pragma unroll
        for (int g = 0; g < 4; ++g) {
            const int d0 = 8 * g + 4 * lg2;
            f16x4 r0 = {(_Float16)(oacc0[4 * g + 0] * inv), (_Float16)(oacc0[4 * g + 1] * inv),
                        (_Float16)(oacc0[4 * g + 2] * inv), (_Float16)(oacc0[4 * g + 3] * inv)};
            f16x4 r1 = {(_Float16)(oacc1[4 * g + 0] * inv), (_Float16)(oacc1[4 * g + 1] * inv),
                        (_Float16)(oacc1[4 * g + 2] * inv), (_Float16)(oacc1[4 * g + 3] * inv)};
            *(f16x4*)(op + d0)      = r0;
            *(f16x4*)(op + 32 + d0) = r1;
        }
    }
}

// ---------------------------------------------------------------------------
__global__ __launch_bounds__(256) void readout_k(
    const _Float16* __restrict__ h, const float* __restrict__ ro,
    float* __restrict__ out, float scale)
{
    const int idx = blockIdx.x * 256 + threadIdx.x;
    const int vv  = idx & (Vc - 1);
    const int bb  = idx >> 11;
    const _Float16* hp = h + (size_t)(bb * Tc + (Tc - 1)) * Dc;
    const float* rp = ro + (size_t)vv * Dc;
    float ax = 0.f, ay = 0.f, az = 0.f, aw = 0.f;
#pragma unroll 8
    for (int i = 0; i < Dc / 4; ++i) {
        f16x4  hv = *(const f16x4*)(hp + i * 4);
        float4 rv = *(const float4*)(rp + i * 4);
        ax = fmaf((float)hv[0], rv.x, ax);
        ay = fmaf((float)hv[1], rv.y, ay);
        az = fmaf((float)hv[2], rv.z, az);
        aw = fmaf((float)hv[3], rv.w, aw);
    }
    out[idx] = ((ax + ay) + (az + aw)) * scale;
}

// ---------------------------------------------------------------------------
extern "C" void kernel_launch(void* const* d_in, const int* in_sizes, int n_in,
                              void* d_out, int out_size, void* d_ws, size_t ws_size,
                              hipStream_t stream)
{
    const float* x    = (const float*)d_in[0];
    const float* temb = (const float*)d_in[1];
    const float* pemb = (const float*)d_in[2];
    const float* Wk   = (const float*)d_in[3];
    const float* Wq   = (const float*)d_in[4];
    const float* Wv   = (const float*)d_in[5];
    const float* Wp   = (const float*)d_in[6];
    const float* ro   = (const float*)d_in[7];
    float* out = (float*)d_out;

    _Float16* h16    = (_Float16*)d_ws;                    // SZe
    _Float16* temb16 = h16 + SZe;                          // 1M
    _Float16* wq16   = temb16 + (size_t)Dc * Vc;           // 1M each
    _Float16* wk16   = wq16 + (size_t)Lc * Dc * Dc;
    _Float16* wv16   = wk16 + (size_t)Lc * Dc * Dc;
    _Float16* wp16   = wv16 + (size_t)Lc * Dc * Dc;
    _Float16* o16    = wp16 + (size_t)Lc * Dc * Dc;        // SZe
    _Float16* qh     = o16 + SZe;
    _Float16* khF    = qh + SZe;                           // frag-major K
    _Float16* vhF    = khF + SZe;                          // frag-major V
    _Float16* x16    = o16;                                // alias, 4*SZe

    const float s_emb  = 1.0f / sqrtf((float)Vc);
    const float s_proj = 1.0f / sqrtf((float)Dc);
    // Q scale: D^-1/2 * HD^-1/2 * log2(e)  (scores in log2 domain)
    const float s_q    = s_proj * 0.125f * 1.44269504f;

    const int W4 = Lc * Dc * Dc / 4;
    cvt_k<<<2048, 256, 0, stream>>>(x, x16, (int)SZe);
    cvt_k<<<512, 256, 0, stream>>>(temb, temb16, Dc * Vc / 4);
    cvtW_k<<<dim3(512, 4), 256, 0, stream>>>(Wq, Wk, Wv, Wp,
                                             wq16, wk16, wv16, wp16, W4);

    // h0 = x @ temb^T * s_emb + pos
    gemm_f16<false><<<dim3(64, 8), 256, 0, stream>>>(
        x16, temb16, nullptr, nullptr, h16, pemb, Vc, s_emb, s_emb, 1, 0, 0);

    const size_t WOFF = (size_t)Dc * Dc;
    for (int lyr = 0; lyr < Lc; ++lyr) {
        const bool last = (lyr == Lc - 1);
        if (!last) {
            gemm_f16<true><<<dim3(64, 24), 256, 0, stream>>>(
                h16, wq16 + lyr * WOFF, wk16 + lyr * WOFF, wv16 + lyr * WOFF,
                qh, nullptr, Dc, s_q, s_proj, 1, 0, 0);

            attn_mfma<<<Bc * Hc * (Tc / 64), 256, 0, stream>>>(qh, khF, vhF, o16, 0);

            gemm_f16<false><<<dim3(64, 8), 256, 0, stream>>>(
                o16, wp16 + lyr * WOFF, nullptr, nullptr, h16, nullptr,
                Dc, s_proj, s_proj, 1, 0, 0);
        } else {
            // K,V full (all tokens feed the softmax)
            gemm_f16<true><<<dim3(64, 16), 256, 0, stream>>>(
                h16, wq16 + lyr * WOFF, wk16 + lyr * WOFF, wv16 + lyr * WOFF,
                qh, nullptr, Dc, s_q, s_proj, 1, 0, 8);
            // Q only for m-blocks holding the last token of each batch
            gemm_f16<true><<<dim3(4, 8), 256, 0, stream>>>(
                h16, wq16 + lyr * WOFF, wk16 + lyr * WOFF, wv16 + lyr * WOFF,
                qh, nullptr, Dc, s_q, s_proj, 16, 15, 0);

            // attention: only the qt=31 tile (rows 1984..2047 per bh)
            attn_mfma<<<Bc * Hc, 256, 0, stream>>>(qh, khF, vhF, o16, 31);

            // Wp: only the 4 m-blocks holding the last token
            gemm_f16<false><<<dim3(4, 8), 256, 0, stream>>>(
                o16, wp16 + lyr * WOFF, nullptr, nullptr, h16, nullptr,
                Dc, s_proj, s_proj, 16, 15, 0);
        }
    }

    readout_k<<<(Bc * Vc) / 256, 256, 0, stream>>>(h16, ro, out, s_proj);
}

// Round 18
// 381.015 us; speedup vs baseline: 1.0700x; 1.0051x over previous
//
#include <hip/hip_runtime.h>
#include <math.h>

typedef __attribute__((ext_vector_type(4)))  float    f32x4;
typedef __attribute__((ext_vector_type(16))) float    f32x16;
typedef __attribute__((ext_vector_type(2)))  _Float16 f16x2;
typedef __attribute__((ext_vector_type(4)))  _Float16 f16x4;
typedef __attribute__((ext_vector_type(8)))  _Float16 f16x8;
typedef __attribute__((ext_vector_type(4)))  unsigned u32x4;

constexpr int Bc  = 4;
constexpr int Tc  = 2048;
constexpr int Vc  = 2048;
constexpr int Dc  = 512;
constexpr int Hc  = 8;
constexpr int HDc = 64;
constexpr int Lc  = 4;
constexpr size_t SZe = (size_t)Bc * Tc * Dc;   // 4,194,304

// Fixed softmax offset (log2 domain). Scores*log2e max ~19; p <= 2^7, f16-safe.
constexpr float SM_C = 12.0f;

__device__ __forceinline__ void gload_lds16(const _Float16* g, _Float16* s) {
    __builtin_amdgcn_global_load_lds(
        (const __attribute__((address_space(1))) void*)g,
        (__attribute__((address_space(3))) void*)s,
        16, 0, 0);
}

__device__ __forceinline__ unsigned cvt_pk_u(float a, float b) {
    return __builtin_bit_cast(unsigned, __builtin_amdgcn_cvt_pkrtz(a, b));
}

// ---------------------------------------------------------------------------
// fp32 -> f16 bulk converts
// ---------------------------------------------------------------------------
__global__ __launch_bounds__(256) void cvt_k(
    const float* __restrict__ in, _Float16* __restrict__ out, int n4)
{
    for (int i = blockIdx.x * 256 + threadIdx.x; i < n4; i += gridDim.x * 256) {
        float4 v = ((const float4*)in)[i];
        f16x4 h = {(_Float16)v.x, (_Float16)v.y, (_Float16)v.z, (_Float16)v.w};
        *(f16x4*)&out[(size_t)i * 4] = h;
    }
}

__global__ __launch_bounds__(256) void cvtW_k(
    const float* __restrict__ a, const float* __restrict__ b,
    const float* __restrict__ c, const float* __restrict__ d,
    _Float16* __restrict__ oa, _Float16* __restrict__ ob,
    _Float16* __restrict__ oc, _Float16* __restrict__ od, int n4)
{
    const float* in; _Float16* out;
    switch (blockIdx.y) {
        case 0:  in = a; out = oa; break;
        case 1:  in = b; out = ob; break;
        case 2:  in = c; out = oc; break;
        default: in = d; out = od; break;
    }
    for (int i = blockIdx.x * 256 + threadIdx.x; i < n4; i += gridDim.x * 256) {
        float4 v = ((const float4*)in)[i];
        f16x4 h = {(_Float16)v.x, (_Float16)v.y, (_Float16)v.z, (_Float16)v.w};
        *(f16x4*)&out[(size_t)i * 4] = h;
    }
}

// ---------------------------------------------------------------------------
// Frag-major K/V global layouts for 32x32x16 MFMA (per bh, tile TT = t>>6,
// 8 blocks x 512 halves per 64-token tile; lane l reads 16B at blk*1024B+l*16B):
//  K blk = ((t>>5)&1)*4 + (d>>4):  lane'=(t&31)+32*((d>>3)&1), j=d&7
//  V blk = (d>>5)*4 + ((t>>4)&3):  lane'=(d&31)+32*((t>>3)&1), j=t&7
// ---------------------------------------------------------------------------

// ---------------------------------------------------------------------------
// Pipelined f16 MFMA GEMM, NT: C = scale * A[M,K] @ W[N,K]^T  (unchanged r17)
// ---------------------------------------------------------------------------
template<bool QKV>
__global__ __launch_bounds__(256) void gemm_f16(
    const _Float16* __restrict__ A,
    const _Float16* __restrict__ W0, const _Float16* __restrict__ W1,
    const _Float16* __restrict__ W2,
    void* __restrict__ C0, const float* __restrict__ pos,
    int K, float scA, float scB, int mstep, int moff, int ybase)
{
    __shared__ __align__(16) _Float16 LA[2][128 * 64];
    __shared__ __align__(16) _Float16 LB[2][64 * 64];

    const int tid = threadIdx.x;
    const int w  = tid >> 6, l = tid & 63;
    const int li = l & 15,  lg = l >> 4;
    const int wm = w >> 1,  wn = w & 1;
    const int m0 = (blockIdx.x * mstep + moff) * 128;
    const int y  = blockIdx.y + ybase;

    int sec = 0, n0;
    const _Float16* Wb;
    if (QKV) {
        sec = y >> 3; n0 = (y & 7) * 64;
        Wb = (sec == 0) ? W0 : ((sec == 1) ? W1 : W2);
    } else {
        n0 = y * 64; Wb = W0;
    }
    const float scale = (sec == 0) ? scA : scB;

    const _Float16* srcA[4];
    const _Float16* srcB[2];
#pragma unroll
    for (int i = 0; i < 4; ++i) {
        const int d = i * 4096 + tid * 16;
        const int r = d >> 7, cb = (d & 127) ^ ((r & 7) << 4);
        srcA[i] = A + (size_t)(m0 + r) * K + (cb >> 1);
    }
#pragma unroll
    for (int i = 0; i < 2; ++i) {
        const int d = i * 4096 + tid * 16;
        const int r = d >> 7, cb = (d & 127) ^ ((r & 7) << 4);
        srcB[i] = Wb + (size_t)(n0 + r) * K + (cb >> 1);
    }

    auto stage = [&](int b) {
#pragma unroll
        for (int i = 0; i < 4; ++i) { gload_lds16(srcA[i], &LA[b][i * 2048 + tid * 8]); srcA[i] += 64; }
#pragma unroll
        for (int i = 0; i < 2; ++i) { gload_lds16(srcB[i], &LB[b][i * 2048 + tid * 8]); srcB[i] += 64; }
    };

    f32x4 acc[4][2];
#pragma unroll
    for (int i = 0; i < 4; ++i)
#pragma unroll
        for (int j = 0; j < 2; ++j) acc[i][j] = (f32x4){0.f, 0.f, 0.f, 0.f};

    auto compute = [&](int b) {
        const char* Ab = (const char*)&LA[b][0];
        const char* Bb = (const char*)&LB[b][0];
        f16x8 af[4][2], bf[2][2];
#pragma unroll
        for (int mb = 0; mb < 4; ++mb) {
            const int row = wm * 64 + mb * 16 + li, sz = (row & 7) << 4;
#pragma unroll
            for (int fi = 0; fi < 2; ++fi)
                af[mb][fi] = *(const f16x8*)(Ab + row * 128 + ((fi * 64 + lg * 16) ^ sz));
        }
#pragma unroll
        for (int nb = 0; nb < 2; ++nb) {
            const int row = wn * 32 + nb * 16 + li, sz = (row & 7) << 4;
#pragma unroll
            for (int fi = 0; fi < 2; ++fi)
                bf[nb][fi] = *(const f16x8*)(Bb + row * 128 + ((fi * 64 + lg * 16) ^ sz));
        }
#pragma unroll
        for (int mb = 0; mb < 4; ++mb)
#pragma unroll
            for (int nb = 0; nb < 2; ++nb)
#pragma unroll
                for (int fi = 0; fi < 2; ++fi)
                    acc[mb][nb] = __builtin_amdgcn_mfma_f32_16x16x32_f16(
                        af[mb][fi], bf[nb][fi], acc[mb][nb], 0, 0, 0);
    };

    const int NTk = K >> 6;
    stage(0);
    for (int kt = 0; kt < NTk; ++kt) {
        const int cur = kt & 1;
        if (kt + 1 < NTk) {
            stage(cur ^ 1);
            asm volatile("s_waitcnt vmcnt(6)" ::: "memory");
        } else {
            asm volatile("s_waitcnt vmcnt(0)" ::: "memory");
        }
        __builtin_amdgcn_s_barrier();
        __builtin_amdgcn_sched_barrier(0);
        compute(cur);
        __builtin_amdgcn_s_barrier();
        __builtin_amdgcn_sched_barrier(0);
    }

    // Epilogue. C/D: col(li) = n, row(lg*4+r) = m.
#pragma unroll
    for (int mb = 0; mb < 4; ++mb) {
#pragma unroll
        for (int nb = 0; nb < 2; ++nb) {
            const int mbase = m0 + wm * 64 + mb * 16 + lg * 4;
            const int nc    = n0 + wn * 32 + nb * 16 + li;
            if (QKV && sec == 2) {        // V frag-major (32x32), f16x4 store
                const int t0 = mbase & (Tc - 1);
                const int bh2 = (mbase >> 11) * Hc + (nc >> 6), d = nc & 63;
                f16x4 vv;
#pragma unroll
                for (int r = 0; r < 4; ++r) vv[r] = (_Float16)(acc[mb][nb][r] * scale);
                _Float16* vf = (_Float16*)C0 + 2 * SZe;
                const size_t adr =
                    (((size_t)bh2 * 32 + (t0 >> 6)) * 8 + (d >> 5) * 4 + ((t0 >> 4) & 3)) * 512
                    + ((d & 31) + 32 * ((t0 >> 3) & 1)) * 8 + (t0 & 7);
                *(f16x4*)&vf[adr] = vv;
            } else if (QKV && sec == 1) { // K frag-major (32x32), 2B scatter
                _Float16* kf = (_Float16*)C0 + SZe;
                const int t0 = mbase & (Tc - 1);
                const int bh2 = (mbase >> 11) * Hc + (nc >> 6), d = nc & 63;
                const size_t adr0 =
                    (((size_t)bh2 * 32 + (t0 >> 6)) * 8 + ((t0 >> 5) & 1) * 4 + (d >> 4)) * 512
                    + ((t0 & 31) + 32 * ((d >> 3) & 1)) * 8 + (d & 7);
#pragma unroll
                for (int r = 0; r < 4; ++r)
                    kf[adr0 + (size_t)r * 8] = (_Float16)(acc[mb][nb][r] * scale);
            } else if (QKV) {             // Q head-separated f16 [BH][T][64]
                _Float16* outp = (_Float16*)C0;
#pragma unroll
                for (int r = 0; r < 4; ++r) {
                    const int m = mbase + r, bb2 = m >> 11, t = m & (Tc - 1);
                    outp[(((size_t)bb2 * Hc + (nc >> 6)) * Tc + t) * HDc + (nc & 63)] =
                        (_Float16)(acc[mb][nb][r] * scale);
                }
            } else {                      // flat f16 [M][512] (+ fp32 pos add)
                _Float16* outp = (_Float16*)C0;
#pragma unroll
                for (int r = 0; r < 4; ++r) {
                    const int m = mbase + r;
                    float val = acc[mb][nb][r] * scale;
                    if (pos) val += pos[(size_t)(m & (Tc - 1)) * Dc + nc];
                    outp[(size_t)m * Dc + nc] = (_Float16)val;
                }
            }
        }
    }
}

// ---------------------------------------------------------------------------
// MFMA flash attention, all-register, 8 waves/block (qhalf, khalf, ktp).
// Wave (qhalf,khalf,ktp) processes k-tiles kt = ktp, ktp+2, ... (16 tiles),
// each a 32q x 32k quadrant.  Max-free softmax -> all combines are pure adds:
// 3-step LDS tree (ktp pair, then khalf pair, then write O).
// 32 waves/CU (8/SIMD) hides the QK->exp2->PV dependency chain.
// ---------------------------------------------------------------------------
__global__ __launch_bounds__(512) void attn_mfma(
    const _Float16* __restrict__ Qh, const _Float16* __restrict__ Kf,
    const _Float16* __restrict__ Vf, _Float16* __restrict__ o, int qtoff)
{
    __shared__ float cm[4 * 64 * 33];   // 33.8 KB combine scratch

    const int bid = blockIdx.x;
    const int bh  = bid & 31;           // XCD-locality: bid%8 == bh%8
    const int qt  = (bid >> 5) + qtoff;
    const int hh  = bh & (Hc - 1);
    const int bb  = bh >> 3;
    const int tid = threadIdx.x;
    const int w   = tid >> 6;
    const int l   = tid & 63;
    const int li  = l & 31, lg2 = l >> 5;
    const int qhalf = w & 1, khalf = (w >> 1) & 1, ktp = w >> 2;
    const int q0  = qt * 64 + qhalf * 32;

    const _Float16* Qb = Qh + (size_t)bh * Tc * HDc;
    f16x8 qf[4];
#pragma unroll
    for (int fi = 0; fi < 4; ++fi)
        qf[fi] = *(const f16x8*)&Qb[(size_t)(q0 + li) * HDc + fi * 16 + lg2 * 8];

    // frag bases at tile ktp; stride 2 tiles = 8192 halves
    const _Float16* Kb  = Kf + (size_t)bh * Tc * HDc + (size_t)ktp * 4096
                          + (khalf * 4) * 512 + l * 8;
    const _Float16* Vb0 = Vf + (size_t)bh * Tc * HDc + (size_t)ktp * 4096
                          + (khalf * 2) * 512 + l * 8;
    const _Float16* Vb1 = Vb0 + 4 * 512;

    f32x16 oacc0, oacc1, lacc, sinit;
#pragma unroll
    for (int i = 0; i < 16; ++i) { oacc0[i] = 0.f; oacc1[i] = 0.f; lacc[i] = 0.f; sinit[i] = -SM_C; }
    f16x8 ones;
#pragma unroll
    for (int i = 0; i < 8; ++i) ones[i] = (_Float16)1.f;

    f16x8 kfr[4], vfr[4];
#pragma unroll
    for (int fi = 0; fi < 4; ++fi) kfr[fi] = *(const f16x8*)(Kb + fi * 512);
#pragma unroll
    for (int m = 0; m < 2; ++m) {
        vfr[m]     = *(const f16x8*)(Vb0 + m * 512);
        vfr[2 + m] = *(const f16x8*)(Vb1 + m * 512);
    }
    Kb += 8192; Vb0 += 8192; Vb1 += 8192;

    constexpr int NT = Tc / 64;   // 32 tiles; this wave does 16
    for (int kt = ktp; kt < NT; kt += 2) {
        __builtin_amdgcn_s_setprio(1);
        f32x16 s = __builtin_amdgcn_mfma_f32_32x32x16_f16(kfr[0], qf[0], sinit, 0, 0, 0);
        s = __builtin_amdgcn_mfma_f32_32x32x16_f16(kfr[1], qf[1], s, 0, 0, 0);
        s = __builtin_amdgcn_mfma_f32_32x32x16_f16(kfr[2], qf[2], s, 0, 0, 0);
        s = __builtin_amdgcn_mfma_f32_32x32x16_f16(kfr[3], qf[3], s, 0, 0, 0);
        __builtin_amdgcn_s_setprio(0);

        if (kt + 2 < NT) {
#pragma unroll
            for (int fi = 0; fi < 4; ++fi) kfr[fi] = *(const f16x8*)(Kb + fi * 512);
            Kb += 8192;
        }

        unsigned cc[8];
#pragma unroll
        for (int g = 0; g < 4; ++g) {
            float p0 = __builtin_amdgcn_exp2f(s[4 * g + 0]);
            float p1 = __builtin_amdgcn_exp2f(s[4 * g + 1]);
            float p2 = __builtin_amdgcn_exp2f(s[4 * g + 2]);
            float p3 = __builtin_amdgcn_exp2f(s[4 * g + 3]);
            cc[2 * g]     = cvt_pk_u(p0, p1);
            cc[2 * g + 1] = cvt_pk_u(p2, p3);
        }

        f16x8 Bf[2];
#pragma unroll
        for (int m = 0; m < 2; ++m) {
            auto u = __builtin_amdgcn_permlane32_swap(cc[m * 4 + 0], cc[m * 4 + 2], false, false);
            auto v = __builtin_amdgcn_permlane32_swap(cc[m * 4 + 1], cc[m * 4 + 3], false, false);
            u32x4 b4 = (u32x4){u[0], v[0], u[1], v[1]};
            Bf[m] = __builtin_bit_cast(f16x8, b4);
        }

        __builtin_amdgcn_s_setprio(1);
        lacc  = __builtin_amdgcn_mfma_f32_32x32x16_f16(ones,   Bf[0], lacc,  0, 0, 0);
        oacc0 = __builtin_amdgcn_mfma_f32_32x32x16_f16(vfr[0], Bf[0], oacc0, 0, 0, 0);
        oacc0 = __builtin_amdgcn_mfma_f32_32x32x16_f16(vfr[1], Bf[1], oacc0, 0, 0, 0);
        lacc  = __builtin_amdgcn_mfma_f32_32x32x16_f16(ones,   Bf[1], lacc,  0, 0, 0);
        oacc1 = __builtin_amdgcn_mfma_f32_32x32x16_f16(vfr[2], Bf[0], oacc1, 0, 0, 0);
        oacc1 = __builtin_amdgcn_mfma_f32_32x32x16_f16(vfr[3], Bf[1], oacc1, 0, 0, 0);
        __builtin_amdgcn_s_setprio(0);

        if (kt + 2 < NT) {
#pragma unroll
            for (int m = 0; m < 2; ++m) {
                vfr[m]     = *(const f16x8*)(Vb0 + m * 512);
                vfr[2 + m] = *(const f16x8*)(Vb1 + m * 512);
            }
            Vb0 += 8192; Vb1 += 8192;
        }
    }

    // ---- combine tree (pure adds thanks to max-free softmax)
    float lrun = lacc[0];               // col q = l&31; both lane-halves hold it
    const int slot = qhalf * 2 + khalf;
    float* cs = cm + slot * (64 * 33) + l * 33;

    // step 1: ktp=1 -> ktp=0 within same (qhalf, khalf)
    if (ktp == 1) {
#pragma unroll
        for (int i = 0; i < 16; ++i) cs[i]      = oacc0[i];
#pragma unroll
        for (int i = 0; i < 16; ++i) cs[16 + i] = oacc1[i];
        cs[32] = lrun;
    }
    __syncthreads();
    if (ktp == 0) {
#pragma unroll
        for (int i = 0; i < 16; ++i) oacc0[i] += cs[i];
#pragma unroll
        for (int i = 0; i < 16; ++i) oacc1[i] += cs[16 + i];
        lrun += cs[32];
    }
    __syncthreads();

    // step 2: khalf=1 -> khalf=0 (ktp=0 waves only), via slot qhalf*2+1
    float* cs2 = cm + (qhalf * 2 + 1) * (64 * 33) + l * 33;
    if (ktp == 0 && khalf == 1) {
#pragma unroll
        for (int i = 0; i < 16; ++i) cs2[i]      = oacc0[i];
#pragma unroll
        for (int i = 0; i < 16; ++i) cs2[16 + i] = oacc1[i];
        cs2[32] = lrun;
    }
    __syncthreads();
    if (ktp == 0 && khalf == 0) {
#pragma unroll
        for (int i = 0; i < 16; ++i) oacc0[i] += cs2[i];
#pragma unroll
        for (int i = 0; i < 16; ++i) oacc1[i] += cs2[16 + i];
        const float inv = 1.f / (lrun + cs2[32]);

        _Float16* op = o + ((size_t)(bb * Tc + q0 + li) * Dc + hh * HDc);
#pragma unroll
        for (int g = 0; g < 4; ++g) {
            const int d0 = 8 * g + 4 * lg2;
            f16x4 r0 = {(_Float16)(oacc0[4 * g + 0] * inv), (_Float16)(oacc0[4 * g + 1] * inv),
                        (_Float16)(oacc0[4 * g + 2] * inv), (_Float16)(oacc0[4 * g + 3] * inv)};
            f16x4 r1 = {(_Float16)(oacc1[4 * g + 0] * inv), (_Float16)(oacc1[4 * g + 1] * inv),
                        (_Float16)(oacc1[4 * g + 2] * inv), (_Float16)(oacc1[4 * g + 3] * inv)};
            *(f16x4*)(op + d0)      = r0;
            *(f16x4*)(op + 32 + d0) = r1;
        }
    }
}

// ---------------------------------------------------------------------------
__global__ __launch_bounds__(256) void readout_k(
    const _Float16* __restrict__ h, const float* __restrict__ ro,
    float* __restrict__ out, float scale)
{
    const int idx = blockIdx.x * 256 + threadIdx.x;
    const int vv  = idx & (Vc - 1);
    const int bb  = idx >> 11;
    const _Float16* hp = h + (size_t)(bb * Tc + (Tc - 1)) * Dc;
    const float* rp = ro + (size_t)vv * Dc;
    float ax = 0.f, ay = 0.f, az = 0.f, aw = 0.f;
#pragma unroll 8
    for (int i = 0; i < Dc / 4; ++i) {
        f16x4  hv = *(const f16x4*)(hp + i * 4);
        float4 rv = *(const float4*)(rp + i * 4);
        ax = fmaf((float)hv[0], rv.x, ax);
        ay = fmaf((float)hv[1], rv.y, ay);
        az = fmaf((float)hv[2], rv.z, az);
        aw = fmaf((float)hv[3], rv.w, aw);
    }
    out[idx] = ((ax + ay) + (az + aw)) * scale;
}

// ---------------------------------------------------------------------------
extern "C" void kernel_launch(void* const* d_in, const int* in_sizes, int n_in,
                              void* d_out, int out_size, void* d_ws, size_t ws_size,
                              hipStream_t stream)
{
    const float* x    = (const float*)d_in[0];
    const float* temb = (const float*)d_in[1];
    const float* pemb = (const float*)d_in[2];
    const float* Wk   = (const float*)d_in[3];
    const float* Wq   = (const float*)d_in[4];
    const float* Wv   = (const float*)d_in[5];
    const float* Wp   = (const float*)d_in[6];
    const float* ro   = (const float*)d_in[7];
    float* out = (float*)d_out;

    _Float16* h16    = (_Float16*)d_ws;                    // SZe
    _Float16* temb16 = h16 + SZe;                          // 1M
    _Float16* wq16   = temb16 + (size_t)Dc * Vc;           // 1M each
    _Float16* wk16   = wq16 + (size_t)Lc * Dc * Dc;
    _Float16* wv16   = wk16 + (size_t)Lc * Dc * Dc;
    _Float16* wp16   = wv16 + (size_t)Lc * Dc * Dc;
    _Float16* o16    = wp16 + (size_t)Lc * Dc * Dc;        // SZe
    _Float16* qh     = o16 + SZe;
    _Float16* khF    = qh + SZe;                           // frag-major K
    _Float16* vhF    = khF + SZe;                          // frag-major V
    _Float16* x16    = o16;                                // alias, 4*SZe

    const float s_emb  = 1.0f / sqrtf((float)Vc);
    const float s_proj = 1.0f / sqrtf((float)Dc);
    // Q scale: D^-1/2 * HD^-1/2 * log2(e)  (scores in log2 domain)
    const float s_q    = s_proj * 0.125f * 1.44269504f;

    const int W4 = Lc * Dc * Dc / 4;
    cvt_k<<<2048, 256, 0, stream>>>(x, x16, (int)SZe);
    cvt_k<<<512, 256, 0, stream>>>(temb, temb16, Dc * Vc / 4);
    cvtW_k<<<dim3(512, 4), 256, 0, stream>>>(Wq, Wk, Wv, Wp,
                                             wq16, wk16, wv16, wp16, W4);

    // h0 = x @ temb^T * s_emb + pos
    gemm_f16<false><<<dim3(64, 8), 256, 0, stream>>>(
        x16, temb16, nullptr, nullptr, h16, pemb, Vc, s_emb, s_emb, 1, 0, 0);

    const size_t WOFF = (size_t)Dc * Dc;
    for (int lyr = 0; lyr < Lc; ++lyr) {
        const bool last = (lyr == Lc - 1);
        if (!last) {
            gemm_f16<true><<<dim3(64, 24), 256, 0, stream>>>(
                h16, wq16 + lyr * WOFF, wk16 + lyr * WOFF, wv16 + lyr * WOFF,
                qh, nullptr, Dc, s_q, s_proj, 1, 0, 0);

            attn_mfma<<<Bc * Hc * (Tc / 64), 512, 0, stream>>>(qh, khF, vhF, o16, 0);

            gemm_f16<false><<<dim3(64, 8), 256, 0, stream>>>(
                o16, wp16 + lyr * WOFF, nullptr, nullptr, h16, nullptr,
                Dc, s_proj, s_proj, 1, 0, 0);
        } else {
            // K,V full (all tokens feed the softmax)
            gemm_f16<true><<<dim3(64, 16), 256, 0, stream>>>(
                h16, wq16 + lyr * WOFF, wk16 + lyr * WOFF, wv16 + lyr * WOFF,
                qh, nullptr, Dc, s_q, s_proj, 1, 0, 8);
            // Q only for m-blocks holding the last token of each batch
            gemm_f16<true><<<dim3(4, 8), 256, 0, stream>>>(
                h16, wq16 + lyr * WOFF, wk16 + lyr * WOFF, wv16 + lyr * WOFF,
                qh, nullptr, Dc, s_q, s_proj, 16, 15, 0);

            // attention: only the qt=31 tile (rows 1984..2047 per bh)
            attn_mfma<<<Bc * Hc, 512, 0, stream>>>(qh, khF, vhF, o16, 31);

            // Wp: only the 4 m-blocks holding the last token
            gemm_f16<false><<<dim3(4, 8), 256, 0, stream>>>(
                o16, wp16 + lyr * WOFF, nullptr, nullptr, h16, nullptr,
                Dc, s_proj, s_proj, 16, 15, 0);
        }
    }

    readout_k<<<(Bc * Vc) / 256, 256, 0, stream>>>(h16, ro, out, s_proj);
}

// Round 19
// 373.150 us; speedup vs baseline: 1.0926x; 1.0211x over previous
//
#include <hip/hip_runtime.h>
#include <math.h>

typedef __attribute__((ext_vector_type(4)))  float    f32x4;
typedef __attribute__((ext_vector_type(16))) float    f32x16;
typedef __attribute__((ext_vector_type(2)))  _Float16 f16x2;
typedef __attribute__((ext_vector_type(4)))  _Float16 f16x4;
typedef __attribute__((ext_vector_type(8)))  _Float16 f16x8;
typedef __attribute__((ext_vector_type(4)))  unsigned u32x4;

constexpr int Bc  = 4;
constexpr int Tc  = 2048;
constexpr int Vc  = 2048;
constexpr int Dc  = 512;
constexpr int Hc  = 8;
constexpr int HDc = 64;
constexpr int Lc  = 4;
constexpr size_t SZe = (size_t)Bc * Tc * Dc;   // 4,194,304

// Fixed softmax offset (log2 domain). Scores*log2e max ~19; p <= 2^7, f16-safe.
constexpr float SM_C = 12.0f;

__device__ __forceinline__ void gload_lds16(const _Float16* g, _Float16* s) {
    __builtin_amdgcn_global_load_lds(
        (const __attribute__((address_space(1))) void*)g,
        (__attribute__((address_space(3))) void*)s,
        16, 0, 0);
}

__device__ __forceinline__ unsigned cvt_pk_u(float a, float b) {
    return __builtin_bit_cast(unsigned, __builtin_amdgcn_cvt_pkrtz(a, b));
}

// ---------------------------------------------------------------------------
// fp32 -> f16 bulk converts
// ---------------------------------------------------------------------------
__global__ __launch_bounds__(256) void cvt_k(
    const float* __restrict__ in, _Float16* __restrict__ out, int n4)
{
    for (int i = blockIdx.x * 256 + threadIdx.x; i < n4; i += gridDim.x * 256) {
        float4 v = ((const float4*)in)[i];
        f16x4 h = {(_Float16)v.x, (_Float16)v.y, (_Float16)v.z, (_Float16)v.w};
        *(f16x4*)&out[(size_t)i * 4] = h;
    }
}

__global__ __launch_bounds__(256) void cvtW_k(
    const float* __restrict__ a, const float* __restrict__ b,
    const float* __restrict__ c, const float* __restrict__ d,
    _Float16* __restrict__ oa, _Float16* __restrict__ ob,
    _Float16* __restrict__ oc, _Float16* __restrict__ od, int n4)
{
    const float* in; _Float16* out;
    switch (blockIdx.y) {
        case 0:  in = a; out = oa; break;
        case 1:  in = b; out = ob; break;
        case 2:  in = c; out = oc; break;
        default: in = d; out = od; break;
    }
    for (int i = blockIdx.x * 256 + threadIdx.x; i < n4; i += gridDim.x * 256) {
        float4 v = ((const float4*)in)[i];
        f16x4 h = {(_Float16)v.x, (_Float16)v.y, (_Float16)v.z, (_Float16)v.w};
        *(f16x4*)&out[(size_t)i * 4] = h;
    }
}

// ---------------------------------------------------------------------------
// BM=64/BN=64 pipelined f16 GEMM (embed): C = scale*A@W^T + pos.
// 256 thr = 4 waves (2x2, 32x32 out each), LDS 32 KB -> 4-5 blocks/CU,
// grid (M/64, N/64) = (128, 8) = 1024 blocks.  Counted vmcnt(4) dbuf.
// ---------------------------------------------------------------------------
__global__ __launch_bounds__(256) void gemm64_k(
    const _Float16* __restrict__ A, const _Float16* __restrict__ W,
    _Float16* __restrict__ C, const float* __restrict__ pos,
    int K, float scale)
{
    __shared__ __align__(16) _Float16 LA[2][64 * 64];
    __shared__ __align__(16) _Float16 LB[2][64 * 64];

    const int tid = threadIdx.x;
    const int w  = tid >> 6, l = tid & 63;
    const int li = l & 15,  lg = l >> 4;
    const int wm = w >> 1,  wn = w & 1;
    const int m0 = blockIdx.x * 64;
    const int n0 = blockIdx.y * 64;

    const _Float16* srcA[2];
    const _Float16* srcB[2];
#pragma unroll
    for (int i = 0; i < 2; ++i) {
        const int d = i * 4096 + tid * 16;
        const int r = d >> 7, cb = (d & 127) ^ ((r & 7) << 4);
        srcA[i] = A + (size_t)(m0 + r) * K + (cb >> 1);
        srcB[i] = W + (size_t)(n0 + r) * K + (cb >> 1);
    }

    auto stage = [&](int b) {
#pragma unroll
        for (int i = 0; i < 2; ++i) { gload_lds16(srcA[i], &LA[b][i * 2048 + tid * 8]); srcA[i] += 64; }
#pragma unroll
        for (int i = 0; i < 2; ++i) { gload_lds16(srcB[i], &LB[b][i * 2048 + tid * 8]); srcB[i] += 64; }
    };

    f32x4 acc[2][2];
#pragma unroll
    for (int i = 0; i < 2; ++i)
#pragma unroll
        for (int j = 0; j < 2; ++j) acc[i][j] = (f32x4){0.f, 0.f, 0.f, 0.f};

    auto compute = [&](int b) {
        const char* Ab = (const char*)&LA[b][0];
        const char* Bb = (const char*)&LB[b][0];
        f16x8 af[2][2], bf[2][2];
#pragma unroll
        for (int mb = 0; mb < 2; ++mb) {
            const int row = wm * 32 + mb * 16 + li, sz = (row & 7) << 4;
#pragma unroll
            for (int fi = 0; fi < 2; ++fi)
                af[mb][fi] = *(const f16x8*)(Ab + row * 128 + ((fi * 64 + lg * 16) ^ sz));
        }
#pragma unroll
        for (int nb = 0; nb < 2; ++nb) {
            const int row = wn * 32 + nb * 16 + li, sz = (row & 7) << 4;
#pragma unroll
            for (int fi = 0; fi < 2; ++fi)
                bf[nb][fi] = *(const f16x8*)(Bb + row * 128 + ((fi * 64 + lg * 16) ^ sz));
        }
#pragma unroll
        for (int mb = 0; mb < 2; ++mb)
#pragma unroll
            for (int nb = 0; nb < 2; ++nb)
#pragma unroll
                for (int fi = 0; fi < 2; ++fi)
                    acc[mb][nb] = __builtin_amdgcn_mfma_f32_16x16x32_f16(
                        af[mb][fi], bf[nb][fi], acc[mb][nb], 0, 0, 0);
    };

    const int NTk = K >> 6;
    stage(0);
    for (int kt = 0; kt < NTk; ++kt) {
        const int cur = kt & 1;
        if (kt + 1 < NTk) {
            stage(cur ^ 1);
            asm volatile("s_waitcnt vmcnt(4)" ::: "memory");
        } else {
            asm volatile("s_waitcnt vmcnt(0)" ::: "memory");
        }
        __builtin_amdgcn_s_barrier();
        __builtin_amdgcn_sched_barrier(0);
        compute(cur);
        __builtin_amdgcn_s_barrier();
        __builtin_amdgcn_sched_barrier(0);
    }

#pragma unroll
    for (int mb = 0; mb < 2; ++mb) {
#pragma unroll
        for (int nb = 0; nb < 2; ++nb) {
            const int mbase = m0 + wm * 32 + mb * 16 + lg * 4;
            const int nc    = n0 + wn * 32 + nb * 16 + li;
#pragma unroll
            for (int r = 0; r < 4; ++r) {
                const int m = mbase + r;
                float val = acc[mb][nb][r] * scale + pos[(size_t)(m & (Tc - 1)) * Dc + nc];
                C[(size_t)m * Dc + nc] = (_Float16)val;
            }
        }
    }
}

// ---------------------------------------------------------------------------
// Frag-major K/V global layouts for 32x32x16 MFMA (per bh, tile TT = t>>6,
// 8 blocks x 512 halves per 64-token tile; lane l reads 16B at blk*1024B+l*16B):
//  K blk = ((t>>5)&1)*4 + (d>>4):  lane'=(t&31)+32*((d>>3)&1), j=d&7
//  V blk = (d>>5)*4 + ((t>>4)&3):  lane'=(d&31)+32*((t>>3)&1), j=t&7
// ---------------------------------------------------------------------------

// ---------------------------------------------------------------------------
// Pipelined f16 MFMA GEMM, NT: C = scale * A[M,K] @ W[N,K]^T  (unchanged r17)
// ---------------------------------------------------------------------------
template<bool QKV>
__global__ __launch_bounds__(256) void gemm_f16(
    const _Float16* __restrict__ A,
    const _Float16* __restrict__ W0, const _Float16* __restrict__ W1,
    const _Float16* __restrict__ W2,
    void* __restrict__ C0, const float* __restrict__ pos,
    int K, float scA, float scB, int mstep, int moff, int ybase)
{
    __shared__ __align__(16) _Float16 LA[2][128 * 64];
    __shared__ __align__(16) _Float16 LB[2][64 * 64];

    const int tid = threadIdx.x;
    const int w  = tid >> 6, l = tid & 63;
    const int li = l & 15,  lg = l >> 4;
    const int wm = w >> 1,  wn = w & 1;
    const int m0 = (blockIdx.x * mstep + moff) * 128;
    const int y  = blockIdx.y + ybase;

    int sec = 0, n0;
    const _Float16* Wb;
    if (QKV) {
        sec = y >> 3; n0 = (y & 7) * 64;
        Wb = (sec == 0) ? W0 : ((sec == 1) ? W1 : W2);
    } else {
        n0 = y * 64; Wb = W0;
    }
    const float scale = (sec == 0) ? scA : scB;

    const _Float16* srcA[4];
    const _Float16* srcB[2];
#pragma unroll
    for (int i = 0; i < 4; ++i) {
        const int d = i * 4096 + tid * 16;
        const int r = d >> 7, cb = (d & 127) ^ ((r & 7) << 4);
        srcA[i] = A + (size_t)(m0 + r) * K + (cb >> 1);
    }
#pragma unroll
    for (int i = 0; i < 2; ++i) {
        const int d = i * 4096 + tid * 16;
        const int r = d >> 7, cb = (d & 127) ^ ((r & 7) << 4);
        srcB[i] = Wb + (size_t)(n0 + r) * K + (cb >> 1);
    }

    auto stage = [&](int b) {
#pragma unroll
        for (int i = 0; i < 4; ++i) { gload_lds16(srcA[i], &LA[b][i * 2048 + tid * 8]); srcA[i] += 64; }
#pragma unroll
        for (int i = 0; i < 2; ++i) { gload_lds16(srcB[i], &LB[b][i * 2048 + tid * 8]); srcB[i] += 64; }
    };

    f32x4 acc[4][2];
#pragma unroll
    for (int i = 0; i < 4; ++i)
#pragma unroll
        for (int j = 0; j < 2; ++j) acc[i][j] = (f32x4){0.f, 0.f, 0.f, 0.f};

    auto compute = [&](int b) {
        const char* Ab = (const char*)&LA[b][0];
        const char* Bb = (const char*)&LB[b][0];
        f16x8 af[4][2], bf[2][2];
#pragma unroll
        for (int mb = 0; mb < 4; ++mb) {
            const int row = wm * 64 + mb * 16 + li, sz = (row & 7) << 4;
#pragma unroll
            for (int fi = 0; fi < 2; ++fi)
                af[mb][fi] = *(const f16x8*)(Ab + row * 128 + ((fi * 64 + lg * 16) ^ sz));
        }
#pragma unroll
        for (int nb = 0; nb < 2; ++nb) {
            const int row = wn * 32 + nb * 16 + li, sz = (row & 7) << 4;
#pragma unroll
            for (int fi = 0; fi < 2; ++fi)
                bf[nb][fi] = *(const f16x8*)(Bb + row * 128 + ((fi * 64 + lg * 16) ^ sz));
        }
#pragma unroll
        for (int mb = 0; mb < 4; ++mb)
#pragma unroll
            for (int nb = 0; nb < 2; ++nb)
#pragma unroll
                for (int fi = 0; fi < 2; ++fi)
                    acc[mb][nb] = __builtin_amdgcn_mfma_f32_16x16x32_f16(
                        af[mb][fi], bf[nb][fi], acc[mb][nb], 0, 0, 0);
    };

    const int NTk = K >> 6;
    stage(0);
    for (int kt = 0; kt < NTk; ++kt) {
        const int cur = kt & 1;
        if (kt + 1 < NTk) {
            stage(cur ^ 1);
            asm volatile("s_waitcnt vmcnt(6)" ::: "memory");
        } else {
            asm volatile("s_waitcnt vmcnt(0)" ::: "memory");
        }
        __builtin_amdgcn_s_barrier();
        __builtin_amdgcn_sched_barrier(0);
        compute(cur);
        __builtin_amdgcn_s_barrier();
        __builtin_amdgcn_sched_barrier(0);
    }

    // Epilogue. C/D: col(li) = n, row(lg*4+r) = m.
#pragma unroll
    for (int mb = 0; mb < 4; ++mb) {
#pragma unroll
        for (int nb = 0; nb < 2; ++nb) {
            const int mbase = m0 + wm * 64 + mb * 16 + lg * 4;
            const int nc    = n0 + wn * 32 + nb * 16 + li;
            if (QKV && sec == 2) {        // V frag-major (32x32), f16x4 store
                const int t0 = mbase & (Tc - 1);
                const int bh2 = (mbase >> 11) * Hc + (nc >> 6), d = nc & 63;
                f16x4 vv;
#pragma unroll
                for (int r = 0; r < 4; ++r) vv[r] = (_Float16)(acc[mb][nb][r] * scale);
                _Float16* vf = (_Float16*)C0 + 2 * SZe;
                const size_t adr =
                    (((size_t)bh2 * 32 + (t0 >> 6)) * 8 + (d >> 5) * 4 + ((t0 >> 4) & 3)) * 512
                    + ((d & 31) + 32 * ((t0 >> 3) & 1)) * 8 + (t0 & 7);
                *(f16x4*)&vf[adr] = vv;
            } else if (QKV && sec == 1) { // K frag-major (32x32), 2B scatter
                _Float16* kf = (_Float16*)C0 + SZe;
                const int t0 = mbase & (Tc - 1);
                const int bh2 = (mbase >> 11) * Hc + (nc >> 6), d = nc & 63;
                const size_t adr0 =
                    (((size_t)bh2 * 32 + (t0 >> 6)) * 8 + ((t0 >> 5) & 1) * 4 + (d >> 4)) * 512
                    + ((t0 & 31) + 32 * ((d >> 3) & 1)) * 8 + (d & 7);
#pragma unroll
                for (int r = 0; r < 4; ++r)
                    kf[adr0 + (size_t)r * 8] = (_Float16)(acc[mb][nb][r] * scale);
            } else if (QKV) {             // Q head-separated f16 [BH][T][64]
                _Float16* outp = (_Float16*)C0;
#pragma unroll
                for (int r = 0; r < 4; ++r) {
                    const int m = mbase + r, bb2 = m >> 11, t = m & (Tc - 1);
                    outp[(((size_t)bb2 * Hc + (nc >> 6)) * Tc + t) * HDc + (nc & 63)] =
                        (_Float16)(acc[mb][nb][r] * scale);
                }
            } else {                      // flat f16 [M][512] (+ fp32 pos add)
                _Float16* outp = (_Float16*)C0;
#pragma unroll
                for (int r = 0; r < 4; ++r) {
                    const int m = mbase + r;
                    float val = acc[mb][nb][r] * scale;
                    if (pos) val += pos[(size_t)(m & (Tc - 1)) * Dc + nc];
                    outp[(size_t)m * Dc + nc] = (_Float16)val;
                }
            }
        }
    }
}

// ---------------------------------------------------------------------------
// MFMA flash attention, all-register, 4 waves (qhalf, khalf) — r17 version.
// ---------------------------------------------------------------------------
__global__ __launch_bounds__(256) void attn_mfma(
    const _Float16* __restrict__ Qh, const _Float16* __restrict__ Kf,
    const _Float16* __restrict__ Vf, _Float16* __restrict__ o, int qtoff)
{
    __shared__ float cm[4224];          // combine only: 2 qhalf x 64 x 33

    const int bid = blockIdx.x;
    const int bh  = bid & 31;           // XCD-locality: bid%8 == bh%8
    const int qt  = (bid >> 5) + qtoff;
    const int hh  = bh & (Hc - 1);
    const int bb  = bh >> 3;
    const int tid = threadIdx.x;
    const int w   = tid >> 6;
    const int l   = tid & 63;
    const int li  = l & 31, lg2 = l >> 5;
    const int qhalf = w & 1, khalf = w >> 1;
    const int q0  = qt * 64 + qhalf * 32;

    const _Float16* Qb = Qh + (size_t)bh * Tc * HDc;
    f16x8 qf[4];
#pragma unroll
    for (int fi = 0; fi < 4; ++fi)
        qf[fi] = *(const f16x8*)&Qb[(size_t)(q0 + li) * HDc + fi * 16 + lg2 * 8];

    const _Float16* Kb  = Kf + (size_t)bh * Tc * HDc + (khalf * 4) * 512 + l * 8;
    const _Float16* Vb0 = Vf + (size_t)bh * Tc * HDc + (khalf * 2) * 512 + l * 8;
    const _Float16* Vb1 = Vb0 + 4 * 512;

    f32x16 oacc0, oacc1, lacc, sinit;
#pragma unroll
    for (int i = 0; i < 16; ++i) { oacc0[i] = 0.f; oacc1[i] = 0.f; lacc[i] = 0.f; sinit[i] = -SM_C; }
    f16x8 ones;
#pragma unroll
    for (int i = 0; i < 8; ++i) ones[i] = (_Float16)1.f;

    f16x8 kfr[4], vfr[4];
#pragma unroll
    for (int fi = 0; fi < 4; ++fi) kfr[fi] = *(const f16x8*)(Kb + fi * 512);
#pragma unroll
    for (int m = 0; m < 2; ++m) {
        vfr[m]     = *(const f16x8*)(Vb0 + m * 512);
        vfr[2 + m] = *(const f16x8*)(Vb1 + m * 512);
    }
    Kb += 4096; Vb0 += 4096; Vb1 += 4096;

    constexpr int NT = Tc / 64;
    for (int kt = 0; kt < NT; ++kt) {
        __builtin_amdgcn_s_setprio(1);
        f32x16 s = __builtin_amdgcn_mfma_f32_32x32x16_f16(kfr[0], qf[0], sinit, 0, 0, 0);
        s = __builtin_amdgcn_mfma_f32_32x32x16_f16(kfr[1], qf[1], s, 0, 0, 0);
        s = __builtin_amdgcn_mfma_f32_32x32x16_f16(kfr[2], qf[2], s, 0, 0, 0);
        s = __builtin_amdgcn_mfma_f32_32x32x16_f16(kfr[3], qf[3], s, 0, 0, 0);
        __builtin_amdgcn_s_setprio(0);

        if (kt + 1 < NT) {
#pragma unroll
            for (int fi = 0; fi < 4; ++fi) kfr[fi] = *(const f16x8*)(Kb + fi * 512);
            Kb += 4096;
        }

        unsigned cc[8];
#pragma unroll
        for (int g = 0; g < 4; ++g) {
            float p0 = __builtin_amdgcn_exp2f(s[4 * g + 0]);
            float p1 = __builtin_amdgcn_exp2f(s[4 * g + 1]);
            float p2 = __builtin_amdgcn_exp2f(s[4 * g + 2]);
            float p3 = __builtin_amdgcn_exp2f(s[4 * g + 3]);
            cc[2 * g]     = cvt_pk_u(p0, p1);
            cc[2 * g + 1] = cvt_pk_u(p2, p3);
        }

        f16x8 Bf[2];
#pragma unroll
        for (int m = 0; m < 2; ++m) {
            auto u = __builtin_amdgcn_permlane32_swap(cc[m * 4 + 0], cc[m * 4 + 2], false, false);
            auto v = __builtin_amdgcn_permlane32_swap(cc[m * 4 + 1], cc[m * 4 + 3], false, false);
            u32x4 b4 = (u32x4){u[0], v[0], u[1], v[1]};
            Bf[m] = __builtin_bit_cast(f16x8, b4);
        }

        __builtin_amdgcn_s_setprio(1);
        lacc  = __builtin_amdgcn_mfma_f32_32x32x16_f16(ones,   Bf[0], lacc,  0, 0, 0);
        oacc0 = __builtin_amdgcn_mfma_f32_32x32x16_f16(vfr[0], Bf[0], oacc0, 0, 0, 0);
        oacc0 = __builtin_amdgcn_mfma_f32_32x32x16_f16(vfr[1], Bf[1], oacc0, 0, 0, 0);
        lacc  = __builtin_amdgcn_mfma_f32_32x32x16_f16(ones,   Bf[1], lacc,  0, 0, 0);
        oacc1 = __builtin_amdgcn_mfma_f32_32x32x16_f16(vfr[2], Bf[0], oacc1, 0, 0, 0);
        oacc1 = __builtin_amdgcn_mfma_f32_32x32x16_f16(vfr[3], Bf[1], oacc1, 0, 0, 0);
        __builtin_amdgcn_s_setprio(0);

        if (kt + 1 < NT) {
#pragma unroll
            for (int m = 0; m < 2; ++m) {
                vfr[m]     = *(const f16x8*)(Vb0 + m * 512);
                vfr[2 + m] = *(const f16x8*)(Vb1 + m * 512);
            }
            Vb0 += 4096; Vb1 += 4096;
        }
    }

    const float lrun_w = lacc[0];       // col q = l&31; both lane-halves hold it
    const int cbase = qhalf * (64 * 33) + l * 33;
    if (khalf == 1) {
#pragma unroll
        for (int i = 0; i < 16; ++i) cm[cbase + i]      = oacc0[i];
#pragma unroll
        for (int i = 0; i < 16; ++i) cm[cbase + 16 + i] = oacc1[i];
        cm[cbase + 32] = lrun_w;
    }
    __syncthreads();
    if (khalf == 0) {
#pragma unroll
        for (int i = 0; i < 16; ++i) oacc0[i] += cm[cbase + i];
#pragma unroll
        for (int i = 0; i < 16; ++i) oacc1[i] += cm[cbase + 16 + i];
        const float inv = 1.f / (lrun_w + cm[cbase + 32]);

        _Float16* op = o + ((size_t)(bb * Tc + q0 + li) * Dc + hh * HDc);
#pragma unroll
        for (int g = 0; g < 4; ++g) {
            const int d0 = 8 * g + 4 * lg2;
            f16x4 r0 = {(_Float16)(oacc0[4 * g + 0] * inv), (_Float16)(oacc0[4 * g + 1] * inv),
                        (_Float16)(oacc0[4 * g + 2] * inv), (_Float16)(oacc0[4 * g + 3] * inv)};
            f16x4 r1 = {(_Float16)(oacc1[4 * g + 0] * inv), (_Float16)(oacc1[4 * g + 1] * inv),
                        (_Float16)(oacc1[4 * g + 2] * inv), (_Float16)(oacc1[4 * g + 3] * inv)};
            *(f16x4*)(op + d0)      = r0;
            *(f16x4*)(op + 32 + d0) = r1;
        }
    }
}

// ---------------------------------------------------------------------------
__global__ __launch_bounds__(256) void readout_k(
    const _Float16* __restrict__ h, const float* __restrict__ ro,
    float* __restrict__ out, float scale)
{
    const int idx = blockIdx.x * 256 + threadIdx.x;
    const int vv  = idx & (Vc - 1);
    const int bb  = idx >> 11;
    const _Float16* hp = h + (size_t)(bb * Tc + (Tc - 1)) * Dc;
    const float* rp = ro + (size_t)vv * Dc;
    float ax = 0.f, ay = 0.f, az = 0.f, aw = 0.f;
#pragma unroll 8
    for (int i = 0; i < Dc / 4; ++i) {
        f16x4  hv = *(const f16x4*)(hp + i * 4);
        float4 rv = *(const float4*)(rp + i * 4);
        ax = fmaf((float)hv[0], rv.x, ax);
        ay = fmaf((float)hv[1], rv.y, ay);
        az = fmaf((float)hv[2], rv.z, az);
        aw = fmaf((float)hv[3], rv.w, aw);
    }
    out[idx] = ((ax + ay) + (az + aw)) * scale;
}

// ---------------------------------------------------------------------------
extern "C" void kernel_launch(void* const* d_in, const int* in_sizes, int n_in,
                              void* d_out, int out_size, void* d_ws, size_t ws_size,
                              hipStream_t stream)
{
    const float* x    = (const float*)d_in[0];
    const float* temb = (const float*)d_in[1];
    const float* pemb = (const float*)d_in[2];
    const float* Wk   = (const float*)d_in[3];
    const float* Wq   = (const float*)d_in[4];
    const float* Wv   = (const float*)d_in[5];
    const float* Wp   = (const float*)d_in[6];
    const float* ro   = (const float*)d_in[7];
    float* out = (float*)d_out;

    _Float16* h16    = (_Float16*)d_ws;                    // SZe
    _Float16* temb16 = h16 + SZe;                          // 1M
    _Float16* wq16   = temb16 + (size_t)Dc * Vc;           // 1M each
    _Float16* wk16   = wq16 + (size_t)Lc * Dc * Dc;
    _Float16* wv16   = wk16 + (size_t)Lc * Dc * Dc;
    _Float16* wp16   = wv16 + (size_t)Lc * Dc * Dc;
    _Float16* o16    = wp16 + (size_t)Lc * Dc * Dc;        // SZe
    _Float16* qh     = o16 + SZe;
    _Float16* khF    = qh + SZe;                           // frag-major K
    _Float16* vhF    = khF + SZe;                          // frag-major V
    _Float16* x16    = o16;                                // alias, 4*SZe

    const float s_emb  = 1.0f / sqrtf((float)Vc);
    const float s_proj = 1.0f / sqrtf((float)Dc);
    // Q scale: D^-1/2 * HD^-1/2 * log2(e)  (scores in log2 domain)
    const float s_q    = s_proj * 0.125f * 1.44269504f;

    const int W4 = Lc * Dc * Dc / 4;
    cvt_k<<<2048, 256, 0, stream>>>(x, x16, (int)SZe);
    cvt_k<<<512, 256, 0, stream>>>(temb, temb16, Dc * Vc / 4);
    cvtW_k<<<dim3(512, 4), 256, 0, stream>>>(Wq, Wk, Wv, Wp,
                                             wq16, wk16, wv16, wp16, W4);

    // h0 = x @ temb^T * s_emb + pos  (BM=64 geometry: 1024 blocks, 4-5/CU)
    gemm64_k<<<dim3(128, 8), 256, 0, stream>>>(x16, temb16, h16, pemb, Vc, s_emb);

    const size_t WOFF = (size_t)Dc * Dc;
    for (int lyr = 0; lyr < Lc; ++lyr) {
        const bool last = (lyr == Lc - 1);
        if (!last) {
            gemm_f16<true><<<dim3(64, 24), 256, 0, stream>>>(
                h16, wq16 + lyr * WOFF, wk16 + lyr * WOFF, wv16 + lyr * WOFF,
                qh, nullptr, Dc, s_q, s_proj, 1, 0, 0);

            attn_mfma<<<Bc * Hc * (Tc / 64), 256, 0, stream>>>(qh, khF, vhF, o16, 0);

            gemm_f16<false><<<dim3(64, 8), 256, 0, stream>>>(
                o16, wp16 + lyr * WOFF, nullptr, nullptr, h16, nullptr,
                Dc, s_proj, s_proj, 1, 0, 0);
        } else {
            // K,V full (all tokens feed the softmax)
            gemm_f16<true><<<dim3(64, 16), 256, 0, stream>>>(
                h16, wq16 + lyr * WOFF, wk16 + lyr * WOFF, wv16 + lyr * WOFF,
                qh, nullptr, Dc, s_q, s_proj, 1, 0, 8);
            // Q only for m-blocks holding the last token of each batch
            gemm_f16<true><<<dim3(4, 8), 256, 0, stream>>>(
                h16, wq16 + lyr * WOFF, wk16 + lyr * WOFF, wv16 + lyr * WOFF,
                qh, nullptr, Dc, s_q, s_proj, 16, 15, 0);

            // attention: only the qt=31 tile (rows 1984..2047 per bh)
            attn_mfma<<<Bc * Hc, 256, 0, stream>>>(qh, khF, vhF, o16, 31);

            // Wp: only the 4 m-blocks holding the last token
            gemm_f16<false><<<dim3(4, 8), 256, 0, stream>>>(
                o16, wp16 + lyr * WOFF, nullptr, nullptr, h16, nullptr,
                Dc, s_proj, s_proj, 16, 15, 0);
        }
    }

    readout_k<<<(Bc * Vc) / 256, 256, 0, stream>>>(h16, ro, out, s_proj);
}

// Round 21
// 372.615 us; speedup vs baseline: 1.0941x; 1.0014x over previous
//
#include <hip/hip_runtime.h>
#include <math.h>

typedef __attribute__((ext_vector_type(4)))  float    f32x4;
typedef __attribute__((ext_vector_type(16))) float    f32x16;
typedef __attribute__((ext_vector_type(2)))  _Float16 f16x2;
typedef __attribute__((ext_vector_type(4)))  _Float16 f16x4;
typedef __attribute__((ext_vector_type(8)))  _Float16 f16x8;
typedef __attribute__((ext_vector_type(4)))  unsigned u32x4;

constexpr int Bc  = 4;
constexpr int Tc  = 2048;
constexpr int Vc  = 2048;
constexpr int Dc  = 512;
constexpr int Hc  = 8;
constexpr int HDc = 64;
constexpr int Lc  = 4;
constexpr size_t SZe = (size_t)Bc * Tc * Dc;   // 4,194,304

// Fixed softmax offset (log2 domain). Scores*log2e max ~19; p <= 2^7, f16-safe.
constexpr float SM_C = 12.0f;

__device__ __forceinline__ void gload_lds16(const _Float16* g, _Float16* s) {
    __builtin_amdgcn_global_load_lds(
        (const __attribute__((address_space(1))) void*)g,
        (__attribute__((address_space(3))) void*)s,
        16, 0, 0);
}

__device__ __forceinline__ unsigned cvt_pk_u(float a, float b) {
    return __builtin_bit_cast(unsigned, __builtin_amdgcn_cvt_pkrtz(a, b));
}

// ---------------------------------------------------------------------------
// Merged fp32 -> f16 bulk convert: blockIdx.y selects the buffer.
// x is B*T*V = 16.78M floats = SZe float4s (bug in r20: had SZe/2).
// ---------------------------------------------------------------------------
__global__ __launch_bounds__(256) void cvtAll_k(
    const float* __restrict__ x,  const float* __restrict__ temb,
    const float* __restrict__ wq, const float* __restrict__ wk,
    const float* __restrict__ wv, const float* __restrict__ wp,
    _Float16* __restrict__ ox,  _Float16* __restrict__ otemb,
    _Float16* __restrict__ owq, _Float16* __restrict__ owk,
    _Float16* __restrict__ owv, _Float16* __restrict__ owp)
{
    const float* in; _Float16* out; int n4;
    switch (blockIdx.y) {
        case 0:  in = x;    out = ox;    n4 = (int)SZe;       break;  // 4,194,304
        case 1:  in = temb; out = otemb; n4 = Dc * Vc / 4;    break;
        case 2:  in = wq;   out = owq;   n4 = Lc * Dc * Dc / 4; break;
        case 3:  in = wk;   out = owk;   n4 = Lc * Dc * Dc / 4; break;
        case 4:  in = wv;   out = owv;   n4 = Lc * Dc * Dc / 4; break;
        default: in = wp;   out = owp;   n4 = Lc * Dc * Dc / 4; break;
    }
    for (int i = blockIdx.x * 256 + threadIdx.x; i < n4; i += gridDim.x * 256) {
        float4 v = ((const float4*)in)[i];
        f16x4 h = {(_Float16)v.x, (_Float16)v.y, (_Float16)v.z, (_Float16)v.w};
        *(f16x4*)&out[(size_t)i * 4] = h;
    }
}

// ---------------------------------------------------------------------------
// Frag-major K/V global layouts for 32x32x16 MFMA (per bh, tile TT = t>>6,
// 8 blocks x 512 halves per 64-token tile; lane l reads 16B at blk*1024B+l*16B):
//  K blk = ((t>>5)&1)*4 + (d>>4):  lane'=(t&31)+32*((d>>3)&1), j=d&7
//  V blk = (d>>5)*4 + ((t>>4)&3):  lane'=(d&31)+32*((t>>3)&1), j=t&7
// ---------------------------------------------------------------------------

// ---------------------------------------------------------------------------
// BM=64/BN=64 pipelined f16 GEMM: C = scale * A[M,K] @ W[N,K]^T.
// 256 thr = 4 waves (2x2, 32x32 out each), 32 KB LDS -> 5 blocks/CU.
// m0 = (blockIdx.x*mstep + moff)*64; y = blockIdx.y + ybase.
// QKV: sec = y>>3 -> {Q,K,V} epilogues; else flat f16 (+ fp32 pos add).
// ---------------------------------------------------------------------------
template<bool QKV>
__global__ __launch_bounds__(256) void gemm64(
    const _Float16* __restrict__ A,
    const _Float16* __restrict__ W0, const _Float16* __restrict__ W1,
    const _Float16* __restrict__ W2,
    void* __restrict__ C0, const float* __restrict__ pos,
    int K, float scA, float scB, int mstep, int moff, int ybase)
{
    __shared__ __align__(16) _Float16 LA[2][64 * 64];
    __shared__ __align__(16) _Float16 LB[2][64 * 64];

    const int tid = threadIdx.x;
    const int w  = tid >> 6, l = tid & 63;
    const int li = l & 15,  lg = l >> 4;
    const int wm = w >> 1,  wn = w & 1;
    const int m0 = (blockIdx.x * mstep + moff) * 64;
    const int y  = blockIdx.y + ybase;

    int sec = 0, n0;
    const _Float16* Wb;
    if (QKV) {
        sec = y >> 3; n0 = (y & 7) * 64;
        Wb = (sec == 0) ? W0 : ((sec == 1) ? W1 : W2);
    } else {
        n0 = y * 64; Wb = W0;
    }
    const float scale = (sec == 0) ? scA : scB;

    const _Float16* srcA[2];
    const _Float16* srcB[2];
#pragma unroll
    for (int i = 0; i < 2; ++i) {
        const int d = i * 4096 + tid * 16;
        const int r = d >> 7, cb = (d & 127) ^ ((r & 7) << 4);
        srcA[i] = A  + (size_t)(m0 + r) * K + (cb >> 1);
        srcB[i] = Wb + (size_t)(n0 + r) * K + (cb >> 1);
    }

    auto stage = [&](int b) {
#pragma unroll
        for (int i = 0; i < 2; ++i) { gload_lds16(srcA[i], &LA[b][i * 2048 + tid * 8]); srcA[i] += 64; }
#pragma unroll
        for (int i = 0; i < 2; ++i) { gload_lds16(srcB[i], &LB[b][i * 2048 + tid * 8]); srcB[i] += 64; }
    };

    f32x4 acc[2][2];
#pragma unroll
    for (int i = 0; i < 2; ++i)
#pragma unroll
        for (int j = 0; j < 2; ++j) acc[i][j] = (f32x4){0.f, 0.f, 0.f, 0.f};

    auto compute = [&](int b) {
        const char* Ab = (const char*)&LA[b][0];
        const char* Bb = (const char*)&LB[b][0];
        f16x8 af[2][2], bf[2][2];
#pragma unroll
        for (int mb = 0; mb < 2; ++mb) {
            const int row = wm * 32 + mb * 16 + li, sz = (row & 7) << 4;
#pragma unroll
            for (int fi = 0; fi < 2; ++fi)
                af[mb][fi] = *(const f16x8*)(Ab + row * 128 + ((fi * 64 + lg * 16) ^ sz));
        }
#pragma unroll
        for (int nb = 0; nb < 2; ++nb) {
            const int row = wn * 32 + nb * 16 + li, sz = (row & 7) << 4;
#pragma unroll
            for (int fi = 0; fi < 2; ++fi)
                bf[nb][fi] = *(const f16x8*)(Bb + row * 128 + ((fi * 64 + lg * 16) ^ sz));
        }
#pragma unroll
        for (int mb = 0; mb < 2; ++mb)
#pragma unroll
            for (int nb = 0; nb < 2; ++nb)
#pragma unroll
                for (int fi = 0; fi < 2; ++fi)
                    acc[mb][nb] = __builtin_amdgcn_mfma_f32_16x16x32_f16(
                        af[mb][fi], bf[nb][fi], acc[mb][nb], 0, 0, 0);
    };

    const int NTk = K >> 6;
    stage(0);
    for (int kt = 0; kt < NTk; ++kt) {
        const int cur = kt & 1;
        if (kt + 1 < NTk) {
            stage(cur ^ 1);
            asm volatile("s_waitcnt vmcnt(4)" ::: "memory");
        } else {
            asm volatile("s_waitcnt vmcnt(0)" ::: "memory");
        }
        __builtin_amdgcn_s_barrier();
        __builtin_amdgcn_sched_barrier(0);
        compute(cur);
        __builtin_amdgcn_s_barrier();
        __builtin_amdgcn_sched_barrier(0);
    }

    // Epilogue. C/D: col(li) = n, row(lg*4+r) = m.
#pragma unroll
    for (int mb = 0; mb < 2; ++mb) {
#pragma unroll
        for (int nb = 0; nb < 2; ++nb) {
            const int mbase = m0 + wm * 32 + mb * 16 + lg * 4;
            const int nc    = n0 + wn * 32 + nb * 16 + li;
            if (QKV && sec == 2) {        // V frag-major (32x32), f16x4 store
                const int t0 = mbase & (Tc - 1);
                const int bh2 = (mbase >> 11) * Hc + (nc >> 6), d = nc & 63;
                f16x4 vv;
#pragma unroll
                for (int r = 0; r < 4; ++r) vv[r] = (_Float16)(acc[mb][nb][r] * scale);
                _Float16* vf = (_Float16*)C0 + 2 * SZe;
                const size_t adr =
                    (((size_t)bh2 * 32 + (t0 >> 6)) * 8 + (d >> 5) * 4 + ((t0 >> 4) & 3)) * 512
                    + ((d & 31) + 32 * ((t0 >> 3) & 1)) * 8 + (t0 & 7);
                *(f16x4*)&vf[adr] = vv;
            } else if (QKV && sec == 1) { // K frag-major (32x32), 2B scatter
                _Float16* kf = (_Float16*)C0 + SZe;
                const int t0 = mbase & (Tc - 1);
                const int bh2 = (mbase >> 11) * Hc + (nc >> 6), d = nc & 63;
                const size_t adr0 =
                    (((size_t)bh2 * 32 + (t0 >> 6)) * 8 + ((t0 >> 5) & 1) * 4 + (d >> 4)) * 512
                    + ((t0 & 31) + 32 * ((d >> 3) & 1)) * 8 + (d & 7);
#pragma unroll
                for (int r = 0; r < 4; ++r)
                    kf[adr0 + (size_t)r * 8] = (_Float16)(acc[mb][nb][r] * scale);
            } else if (QKV) {             // Q head-separated f16 [BH][T][64]
                _Float16* outp = (_Float16*)C0;
#pragma unroll
                for (int r = 0; r < 4; ++r) {
                    const int m = mbase + r, bb2 = m >> 11, t = m & (Tc - 1);
                    outp[(((size_t)bb2 * Hc + (nc >> 6)) * Tc + t) * HDc + (nc & 63)] =
                        (_Float16)(acc[mb][nb][r] * scale);
                }
            } else {                      // flat f16 [M][512] (+ fp32 pos add)
                _Float16* outp = (_Float16*)C0;
#pragma unroll
                for (int r = 0; r < 4; ++r) {
                    const int m = mbase + r;
                    float val = acc[mb][nb][r] * scale;
                    if (pos) val += pos[(size_t)(m & (Tc - 1)) * Dc + nc];
                    outp[(size_t)m * Dc + nc] = (_Float16)val;
                }
            }
        }
    }
}

// ---------------------------------------------------------------------------
// MFMA flash attention, all-register, 4 waves (qhalf, khalf) — r17 version.
// ---------------------------------------------------------------------------
__global__ __launch_bounds__(256) void attn_mfma(
    const _Float16* __restrict__ Qh, const _Float16* __restrict__ Kf,
    const _Float16* __restrict__ Vf, _Float16* __restrict__ o, int qtoff)
{
    __shared__ float cm[4224];          // combine only: 2 qhalf x 64 x 33

    const int bid = blockIdx.x;
    const int bh  = bid & 31;           // XCD-locality: bid%8 == bh%8
    const int qt  = (bid >> 5) + qtoff;
    const int hh  = bh & (Hc - 1);
    const int bb  = bh >> 3;
    const int tid = threadIdx.x;
    const int w   = tid >> 6;
    const int l   = tid & 63;
    const int li  = l & 31, lg2 = l >> 5;
    const int qhalf = w & 1, khalf = w >> 1;
    const int q0  = qt * 64 + qhalf * 32;

    const _Float16* Qb = Qh + (size_t)bh * Tc * HDc;
    f16x8 qf[4];
#pragma unroll
    for (int fi = 0; fi < 4; ++fi)
        qf[fi] = *(const f16x8*)&Qb[(size_t)(q0 + li) * HDc + fi * 16 + lg2 * 8];

    const _Float16* Kb  = Kf + (size_t)bh * Tc * HDc + (khalf * 4) * 512 + l * 8;
    const _Float16* Vb0 = Vf + (size_t)bh * Tc * HDc + (khalf * 2) * 512 + l * 8;
    const _Float16* Vb1 = Vb0 + 4 * 512;

    f32x16 oacc0, oacc1, lacc, sinit;
#pragma unroll
    for (int i = 0; i < 16; ++i) { oacc0[i] = 0.f; oacc1[i] = 0.f; lacc[i] = 0.f; sinit[i] = -SM_C; }
    f16x8 ones;
#pragma unroll
    for (int i = 0; i < 8; ++i) ones[i] = (_Float16)1.f;

    f16x8 kfr[4], vfr[4];
#pragma unroll
    for (int fi = 0; fi < 4; ++fi) kfr[fi] = *(const f16x8*)(Kb + fi * 512);
#pragma unroll
    for (int m = 0; m < 2; ++m) {
        vfr[m]     = *(const f16x8*)(Vb0 + m * 512);
        vfr[2 + m] = *(const f16x8*)(Vb1 + m * 512);
    }
    Kb += 4096; Vb0 += 4096; Vb1 += 4096;

    constexpr int NT = Tc / 64;
    for (int kt = 0; kt < NT; ++kt) {
        __builtin_amdgcn_s_setprio(1);
        f32x16 s = __builtin_amdgcn_mfma_f32_32x32x16_f16(kfr[0], qf[0], sinit, 0, 0, 0);
        s = __builtin_amdgcn_mfma_f32_32x32x16_f16(kfr[1], qf[1], s, 0, 0, 0);
        s = __builtin_amdgcn_mfma_f32_32x32x16_f16(kfr[2], qf[2], s, 0, 0, 0);
        s = __builtin_amdgcn_mfma_f32_32x32x16_f16(kfr[3], qf[3], s, 0, 0, 0);
        __builtin_amdgcn_s_setprio(0);

        if (kt + 1 < NT) {
#pragma unroll
            for (int fi = 0; fi < 4; ++fi) kfr[fi] = *(const f16x8*)(Kb + fi * 512);
            Kb += 4096;
        }

        unsigned cc[8];
#pragma unroll
        for (int g = 0; g < 4; ++g) {
            float p0 = __builtin_amdgcn_exp2f(s[4 * g + 0]);
            float p1 = __builtin_amdgcn_exp2f(s[4 * g + 1]);
            float p2 = __builtin_amdgcn_exp2f(s[4 * g + 2]);
            float p3 = __builtin_amdgcn_exp2f(s[4 * g + 3]);
            cc[2 * g]     = cvt_pk_u(p0, p1);
            cc[2 * g + 1] = cvt_pk_u(p2, p3);
        }

        f16x8 Bf[2];
#pragma unroll
        for (int m = 0; m < 2; ++m) {
            auto u = __builtin_amdgcn_permlane32_swap(cc[m * 4 + 0], cc[m * 4 + 2], false, false);
            auto v = __builtin_amdgcn_permlane32_swap(cc[m * 4 + 1], cc[m * 4 + 3], false, false);
            u32x4 b4 = (u32x4){u[0], v[0], u[1], v[1]};
            Bf[m] = __builtin_bit_cast(f16x8, b4);
        }

        __builtin_amdgcn_s_setprio(1);
        lacc  = __builtin_amdgcn_mfma_f32_32x32x16_f16(ones,   Bf[0], lacc,  0, 0, 0);
        oacc0 = __builtin_amdgcn_mfma_f32_32x32x16_f16(vfr[0], Bf[0], oacc0, 0, 0, 0);
        oacc0 = __builtin_amdgcn_mfma_f32_32x32x16_f16(vfr[1], Bf[1], oacc0, 0, 0, 0);
        lacc  = __builtin_amdgcn_mfma_f32_32x32x16_f16(ones,   Bf[1], lacc,  0, 0, 0);
        oacc1 = __builtin_amdgcn_mfma_f32_32x32x16_f16(vfr[2], Bf[0], oacc1, 0, 0, 0);
        oacc1 = __builtin_amdgcn_mfma_f32_32x32x16_f16(vfr[3], Bf[1], oacc1, 0, 0, 0);
        __builtin_amdgcn_s_setprio(0);

        if (kt + 1 < NT) {
#pragma unroll
            for (int m = 0; m < 2; ++m) {
                vfr[m]     = *(const f16x8*)(Vb0 + m * 512);
                vfr[2 + m] = *(const f16x8*)(Vb1 + m * 512);
            }
            Vb0 += 4096; Vb1 += 4096;
        }
    }

    const float lrun_w = lacc[0];       // col q = l&31; both lane-halves hold it
    const int cbase = qhalf * (64 * 33) + l * 33;
    if (khalf == 1) {
#pragma unroll
        for (int i = 0; i < 16; ++i) cm[cbase + i]      = oacc0[i];
#pragma unroll
        for (int i = 0; i < 16; ++i) cm[cbase + 16 + i] = oacc1[i];
        cm[cbase + 32] = lrun_w;
    }
    __syncthreads();
    if (khalf == 0) {
#pragma unroll
        for (int i = 0; i < 16; ++i) oacc0[i] += cm[cbase + i];
#pragma unroll
        for (int i = 0; i < 16; ++i) oacc1[i] += cm[cbase + 16 + i];
        const float inv = 1.f / (lrun_w + cm[cbase + 32]);

        _Float16* op = o + ((size_t)(bb * Tc + q0 + li) * Dc + hh * HDc);
#pragma unroll
        for (int g = 0; g < 4; ++g) {
            const int d0 = 8 * g + 4 * lg2;
            f16x4 r0 = {(_Float16)(oacc0[4 * g + 0] * inv), (_Float16)(oacc0[4 * g + 1] * inv),
                        (_Float16)(oacc0[4 * g + 2] * inv), (_Float16)(oacc0[4 * g + 3] * inv)};
            f16x4 r1 = {(_Float16)(oacc1[4 * g + 0] * inv), (_Float16)(oacc1[4 * g + 1] * inv),
                        (_Float16)(oacc1[4 * g + 2] * inv), (_Float16)(oacc1[4 * g + 3] * inv)};
            *(f16x4*)(op + d0)      = r0;
            *(f16x4*)(op + 32 + d0) = r1;
        }
    }
}

// ---------------------------------------------------------------------------
__global__ __launch_bounds__(256) void readout_k(
    const _Float16* __restrict__ h, const float* __restrict__ ro,
    float* __restrict__ out, float scale)
{
    const int idx = blockIdx.x * 256 + threadIdx.x;
    const int vv  = idx & (Vc - 1);
    const int bb  = idx >> 11;
    const _Float16* hp = h + (size_t)(bb * Tc + (Tc - 1)) * Dc;
    const float* rp = ro + (size_t)vv * Dc;
    float ax = 0.f, ay = 0.f, az = 0.f, aw = 0.f;
#pragma unroll 8
    for (int i = 0; i < Dc / 4; ++i) {
        f16x4  hv = *(const f16x4*)(hp + i * 4);
        float4 rv = *(const float4*)(rp + i * 4);
        ax = fmaf((float)hv[0], rv.x, ax);
        ay = fmaf((float)hv[1], rv.y, ay);
        az = fmaf((float)hv[2], rv.z, az);
        aw = fmaf((float)hv[3], rv.w, aw);
    }
    out[idx] = ((ax + ay) + (az + aw)) * scale;
}

// ---------------------------------------------------------------------------
extern "C" void kernel_launch(void* const* d_in, const int* in_sizes, int n_in,
                              void* d_out, int out_size, void* d_ws, size_t ws_size,
                              hipStream_t stream)
{
    const float* x    = (const float*)d_in[0];
    const float* temb = (const float*)d_in[1];
    const float* pemb = (const float*)d_in[2];
    const float* Wk   = (const float*)d_in[3];
    const float* Wq   = (const float*)d_in[4];
    const float* Wv   = (const float*)d_in[5];
    const float* Wp   = (const float*)d_in[6];
    const float* ro   = (const float*)d_in[7];
    float* out = (float*)d_out;

    _Float16* h16    = (_Float16*)d_ws;                    // SZe
    _Float16* temb16 = h16 + SZe;                          // 1M
    _Float16* wq16   = temb16 + (size_t)Dc * Vc;           // 1M each
    _Float16* wk16   = wq16 + (size_t)Lc * Dc * Dc;
    _Float16* wv16   = wk16 + (size_t)Lc * Dc * Dc;
    _Float16* wp16   = wv16 + (size_t)Lc * Dc * Dc;
    _Float16* o16    = wp16 + (size_t)Lc * Dc * Dc;        // SZe
    _Float16* qh     = o16 + SZe;
    _Float16* khF    = qh + SZe;                           // frag-major K
    _Float16* vhF    = khF + SZe;                          // frag-major V
    _Float16* x16    = o16;                                // alias, 4*SZe

    const float s_emb  = 1.0f / sqrtf((float)Vc);
    const float s_proj = 1.0f / sqrtf((float)Dc);
    // Q scale: D^-1/2 * HD^-1/2 * log2(e)  (scores in log2 domain)
    const float s_q    = s_proj * 0.125f * 1.44269504f;

    cvtAll_k<<<dim3(1024, 6), 256, 0, stream>>>(
        x, temb, Wq, Wk, Wv, Wp, x16, temb16, wq16, wk16, wv16, wp16);

    // h0 = x @ temb^T * s_emb + pos  (grid 1024 = 4-5 blocks/CU)
    gemm64<false><<<dim3(128, 8), 256, 0, stream>>>(
        x16, temb16, nullptr, nullptr, h16, pemb, Vc, s_emb, s_emb, 1, 0, 0);

    const size_t WOFF = (size_t)Dc * Dc;
    for (int lyr = 0; lyr < Lc; ++lyr) {
        const bool last = (lyr == Lc - 1);
        if (!last) {
            gemm64<true><<<dim3(128, 24), 256, 0, stream>>>(
                h16, wq16 + lyr * WOFF, wk16 + lyr * WOFF, wv16 + lyr * WOFF,
                qh, nullptr, Dc, s_q, s_proj, 1, 0, 0);

            attn_mfma<<<Bc * Hc * (Tc / 64), 256, 0, stream>>>(qh, khF, vhF, o16, 0);

            gemm64<false><<<dim3(128, 8), 256, 0, stream>>>(
                o16, wp16 + lyr * WOFF, nullptr, nullptr, h16, nullptr,
                Dc, s_proj, s_proj, 1, 0, 0);
        } else {
            // K,V full (all tokens feed the softmax)
            gemm64<true><<<dim3(128, 16), 256, 0, stream>>>(
                h16, wq16 + lyr * WOFF, wk16 + lyr * WOFF, wv16 + lyr * WOFF,
                qh, nullptr, Dc, s_q, s_proj, 1, 0, 8);
            // Q only for 64-blocks holding the last token of each batch
            // (rows 1984..2047 per batch -> blocks 31, 63, 95, 127)
            gemm64<true><<<dim3(4, 8), 256, 0, stream>>>(
                h16, wq16 + lyr * WOFF, wk16 + lyr * WOFF, wv16 + lyr * WOFF,
                qh, nullptr, Dc, s_q, s_proj, 32, 31, 0);

            // attention: only the qt=31 tile (rows 1984..2047 per bh)
            attn_mfma<<<Bc * Hc, 256, 0, stream>>>(qh, khF, vhF, o16, 31);

            // Wp: only the 4 m-blocks holding the last token
            gemm64<false><<<dim3(4, 8), 256, 0, stream>>>(
                o16, wp16 + lyr * WOFF, nullptr, nullptr, h16, nullptr,
                Dc, s_proj, s_proj, 32, 31, 0);
        }
    }

    readout_k<<<(Bc * Vc) / 256, 256, 0, stream>>>(h16, ro, out, s_proj);
}